// Round 7
// baseline (463.407 us; speedup 1.0000x reference)
//
#include <hip/hip_runtime.h>

#define DEVINL __device__ __forceinline__

DEVINL float leaky(float v) { return v >= 0.f ? v : 0.2f * v; }

// ---------------------------------------------------------------------------
// Precompute per-level head projection vectors (unchanged).
// ---------------------------------------------------------------------------
__global__ void wprep_kernel(const float* __restrict__ lin,   // (6,64,64)
                             const float* __restrict__ asrc,  // (6,4,16)
                             const float* __restrict__ adst,  // (6,4,16)
                             float* __restrict__ w_out) {     // (6,2,4,64)
    int idx = blockIdx.x * blockDim.x + threadIdx.x;
    if (idx >= 6 * 4 * 64) return;
    int c = idx & 63;
    int h = (idx >> 6) & 3;
    int k = idx >> 8;
    const float* L = lin + k * 64 * 64;
    float s1 = 0.f, s2 = 0.f;
    for (int e = 0; e < 16; ++e) {
        float w = L[(h * 16 + e) * 64 + c];
        s1 += w * asrc[(k * 4 + h) * 16 + e];
        s2 += w * adst[(k * 4 + h) * 16 + e];
    }
    w_out[(k * 2 + 0) * 256 + h * 64 + c] = s1;
    w_out[(k * 2 + 1) * 256 + h * 64 + c] = s2;
}

// ---------------------------------------------------------------------------
// Transpose pool weights once (unchanged).
// ---------------------------------------------------------------------------
__global__ void wtrans_kernel(const float* __restrict__ s0, const float* __restrict__ s1,
                              const float* __restrict__ t0, const float* __restrict__ t1,
                              const float* __restrict__ s0w2, const float* __restrict__ s1w2,
                              const float* __restrict__ t0w2, const float* __restrict__ t1w2,
                              float* __restrict__ o) {
    int idx = blockIdx.x * 256 + threadIdx.x;
    if (idx < 16384) {
        int m = idx >> 12, r = idx & 4095, c = r >> 6, d = r & 63;
        const float* src = (m == 0) ? s0 : (m == 1) ? s1 : (m == 2) ? t0 : t1;
        o[idx] = src[d * 64 + c];
    } else if (idx < 16384 + 768) {
        int j = idx - 16384, c = j / 12, k = j - 12 * c;
        o[idx] = s0w2[k * 64 + c];
    } else if (idx < 17152 + 512) {
        int j = idx - 17152, c = j >> 3, k = j & 7;
        o[idx] = (k < 5) ? s1w2[k * 64 + c] : 0.f;
    } else if (idx < 17664 + 2048) {
        int j = idx - 17664, c = j >> 5, k = j & 31;
        o[idx] = t0w2[k * 64 + c];
    } else if (idx < 19712 + 768) {
        int j = idx - 19712, c = j / 12, k = j - 12 * c;
        o[idx] = t1w2[k * 64 + c];
    }
}

// ---------------------------------------------------------------------------
// Transpose + level-0 score emission. src (B=64, C=64, T=64, J=25).
// ---------------------------------------------------------------------------
__global__ __launch_bounds__(256) void xs_kernel(
    const float* __restrict__ src, const float* __restrict__ w,
    float* __restrict__ xs, float* __restrict__ sc) {
    int g = blockIdx.x;             // b*64 + t
    int b = g >> 6, t = g & 63;
    __shared__ float tile[64 * 26];  // [c][j]
    __shared__ float wl[512];
    const float* sp = src + b * 102400 + t * 25;
    for (int idx = threadIdx.x; idx < 1600; idx += 256) {
        int c = idx / 25, j = idx - c * 25;
        tile[c * 26 + j] = sp[c * 1600 + j];
    }
    for (int i = threadIdx.x; i < 512; i += 256) wl[i] = w[i];
    __syncthreads();
    float* op = xs + (size_t)g * 1600;
    for (int idx = threadIdx.x; idx < 1600; idx += 256) {
        int j = idx >> 6, c = idx & 63;
        op[idx] = tile[c * 26 + j];
    }
    for (int p = threadIdx.x; p < 200; p += 256) {
        int q = p / 25, n = p - q * 25;
        const float* wp = wl + q * 64;
        float acc = 0.f;
        #pragma unroll 8
        for (int c = 0; c < 64; ++c) acc += tile[c * 26 + n] * wp[c];
        sc[(size_t)g * 200 + p] = acc;
    }
}

__global__ __launch_bounds__(256) void xt_kernel(
    const float* __restrict__ src, const float* __restrict__ w,
    float* __restrict__ xt, float* __restrict__ sc) {
    int g = blockIdx.x;             // b*25 + j
    int b = g / 25, j = g - b * 25;
    __shared__ float tile[64 * 65];  // [c][t]
    __shared__ float wl[512];
    const float* sp = src + b * 102400 + j;
    for (int idx = threadIdx.x; idx < 4096; idx += 256) {
        int c = idx >> 6, t = idx & 63;
        tile[c * 65 + t] = sp[c * 1600 + t * 25];
    }
    for (int i = threadIdx.x; i < 512; i += 256) wl[i] = w[i];
    __syncthreads();
    float* op = xt + (size_t)g * 4096;
    for (int idx = threadIdx.x; idx < 4096; idx += 256) {
        int t = idx >> 6, c = idx & 63;
        op[idx] = tile[c * 65 + t];
    }
    for (int p = threadIdx.x; p < 512; p += 256) {
        int q = p >> 6, n = p & 63;
        const float* wp = wl + q * 64;
        float acc = 0.f;
        #pragma unroll 8
        for (int c = 0; c < 64; ++c) acc += tile[c * 65 + n] * wp[c];
        sc[(size_t)g * 512 + p] = acc;
    }
}

// ---------------------------------------------------------------------------
// Lean diff-pool: x (G,N,64) -> xo (G,K,64) + scores of xo.
// y computed in NH-row halves; xoL aliases yh. LDS: N*68+NH*68+N*(KP+1)+512.
// ---------------------------------------------------------------------------
template <int N, int NH, int K, int KP, int WR>
__global__ __launch_bounds__(256, 3) void pool_kernel(
    const float* __restrict__ x, const float* __restrict__ W1T,
    const float* __restrict__ b1, const float* __restrict__ W2T,
    const float* __restrict__ b2, const float* __restrict__ wso,
    float* __restrict__ xo, float* __restrict__ sco)
{
    static_assert(K <= NH && (N % NH) == 0, "layout");
    constexpr int SLD = KP + 1;
    constexpr int YH = N * 68;
    constexpr int SN = YH + NH * 68;
    constexpr int WLO = SN + N * SLD;
    __shared__ float lds[WLO + 512];
    float* xln = lds;
    float* yh  = lds + YH;
    float* sn  = lds + SN;
    float* wlo = lds + WLO;
    float* xoL = yh;   // alias (K <= NH), yh dead before GEMM3 writes
    const int g = blockIdx.x, tid = threadIdx.x;

    const float4* xp = (const float4*)(x + (size_t)g * N * 64);
    for (int p = tid; p < N * 16; p += 256) {
        int n = p >> 4, c0 = (p & 15) << 2;
        *(float4*)&xln[n * 68 + c0] = xp[p];
    }
    for (int i = tid; i < 512; i += 256) wlo[i] = wso[i];
    __syncthreads();

    #pragma unroll
    for (int h0 = 0; h0 < N; h0 += NH) {
        // GEMM1: y[n][d] = relu(x@W1^T + b1), rows h0..h0+NH-1
        for (int p = tid; p < NH * 16; p += 256) {
            int nl = p >> 4, d0 = (p & 15) << 2;
            const float* xr = &xln[(h0 + nl) * 68];
            float4 bb = *(const float4*)(b1 + d0);
            float a0 = bb.x, a1 = bb.y, a2 = bb.z, a3 = bb.w;
            #pragma unroll 4
            for (int c0 = 0; c0 < 64; c0 += 4) {
                float4 xv = *(const float4*)&xr[c0];
                float4 w0 = *(const float4*)(W1T + (c0 + 0) * 64 + d0);
                float4 w1 = *(const float4*)(W1T + (c0 + 1) * 64 + d0);
                float4 w2 = *(const float4*)(W1T + (c0 + 2) * 64 + d0);
                float4 w3 = *(const float4*)(W1T + (c0 + 3) * 64 + d0);
                a0 += xv.x * w0.x + xv.y * w1.x + xv.z * w2.x + xv.w * w3.x;
                a1 += xv.x * w0.y + xv.y * w1.y + xv.z * w2.y + xv.w * w3.y;
                a2 += xv.x * w0.z + xv.y * w1.z + xv.z * w2.z + xv.w * w3.z;
                a3 += xv.x * w0.w + xv.y * w1.w + xv.z * w2.w + xv.w * w3.w;
            }
            *(float4*)&yh[nl * 68 + d0] =
                make_float4(fmaxf(a0, 0.f), fmaxf(a1, 0.f), fmaxf(a2, 0.f), fmaxf(a3, 0.f));
        }
        __syncthreads();
        // GEMM2: s = y @ W2^T + b2 (pad k -> -1e30)
        for (int p = tid; p < NH * (KP / 4); p += 256) {
            int nl = p / (KP / 4), k0 = (p % (KP / 4)) << 2;
            const float* yr = &yh[nl * 68];
            float a0 = 0.f, a1 = 0.f, a2 = 0.f, a3 = 0.f;
            #pragma unroll 4
            for (int d0 = 0; d0 < 64; d0 += 4) {
                float4 yv = *(const float4*)&yr[d0];
                float4 w0 = *(const float4*)(W2T + (d0 + 0) * KP + k0);
                float4 w1 = *(const float4*)(W2T + (d0 + 1) * KP + k0);
                float4 w2 = *(const float4*)(W2T + (d0 + 2) * KP + k0);
                float4 w3 = *(const float4*)(W2T + (d0 + 3) * KP + k0);
                a0 += yv.x * w0.x + yv.y * w1.x + yv.z * w2.x + yv.w * w3.x;
                a1 += yv.x * w0.y + yv.y * w1.y + yv.z * w2.y + yv.w * w3.y;
                a2 += yv.x * w0.z + yv.y * w1.z + yv.z * w2.z + yv.w * w3.z;
                a3 += yv.x * w0.w + yv.y * w1.w + yv.z * w2.w + yv.w * w3.w;
            }
            float* sr = &sn[(h0 + nl) * SLD + k0];
            sr[0] = (k0 + 0 < K) ? a0 + b2[k0 + 0] : -1e30f;
            sr[1] = (k0 + 1 < K) ? a1 + b2[k0 + 1] : -1e30f;
            sr[2] = (k0 + 2 < K) ? a2 + b2[k0 + 2] : -1e30f;
            sr[3] = (k0 + 3 < K) ? a3 + b2[k0 + 3] : -1e30f;
        }
        __syncthreads();
    }

    // ---- softmax over k per row
    if (tid < N) {
        float* sr = &sn[tid * SLD];
        float m = sr[0];
        #pragma unroll
        for (int k = 1; k < KP; ++k) m = fmaxf(m, sr[k]);
        float sum = 0.f;
        #pragma unroll
        for (int k = 0; k < KP; ++k) { float e = __expf(sr[k] - m); sr[k] = e; sum += e; }
        float inv = 1.f / sum;
        #pragma unroll
        for (int k = 0; k < KP; ++k) sr[k] *= inv;
    }
    __syncthreads();

    // ---- GEMM3: xo[k][c] = sum_n s[n][k] * x[n][c]  (writes xoL = yh alias)
    for (int p = tid; p < K * 16; p += 256) {
        int k = p >> 4, c0 = (p & 15) << 2;
        float a0 = 0.f, a1 = 0.f, a2 = 0.f, a3 = 0.f;
        for (int n = 0; n < N; ++n) {
            float s = sn[n * SLD + k];
            float4 xv = *(const float4*)&xln[n * 68 + c0];
            a0 += s * xv.x; a1 += s * xv.y; a2 += s * xv.z; a3 += s * xv.w;
        }
        float4 r = make_float4(a0, a1, a2, a3);
        *(float4*)&xoL[k * 68 + c0] = r;
        if constexpr (WR)
            *(float4*)(xo + (size_t)g * K * 64 + k * 64 + c0) = r;
    }
    __syncthreads();

    // ---- scores of xo
    for (int p = tid; p < 8 * K; p += 256) {
        int q = p / K, k = p - q * K;
        const float* wv = wlo + q * 64;
        const float* xr = &xoL[k * 68];
        float acc = 0.f;
        #pragma unroll
        for (int c0 = 0; c0 < 64; c0 += 4) {
            float4 xv = *(const float4*)&xr[c0];
            float4 w4 = *(const float4*)&wv[c0];
            acc += xv.x * w4.x + xv.y * w4.y + xv.z * w4.z + xv.w * w4.w;
        }
        sco[(size_t)g * 8 * K + p] = acc;
    }
}

// ---------------------------------------------------------------------------
// Fused GAT0 + low-rank fuse, temporal. Rank-1 factored softmax (unchanged).
// ---------------------------------------------------------------------------
__global__ __launch_bounds__(256, 8) void gatfuse_t(
    const float* __restrict__ sc0,  // (1600,8,64)
    const float* __restrict__ sc1,  // (1600,8,32)
    const float* __restrict__ sc2,  // (1600,8,12)
    const float* __restrict__ L1,   // (4,64,32)
    const float* __restrict__ R1,   // (4,32,64)
    const float* __restrict__ L2,   // (4,64,12)
    const float* __restrict__ R2,   // (4,12,64)
    float* __restrict__ out)        // (1600,4,64,64)
{
    const int bid = blockIdx.x;
    const int g = (bid & 7) | ((bid >> 5) << 3);
    const int h = (bid >> 3) & 3;
    const int tid = threadIdx.x;
    __shared__ float t1T[32 * 64];   // [l][j]
    __shared__ float t2T[12 * 64];   // [l][j]
    __shared__ float A1[32 * 36];    // [k][l]
    __shared__ float A2[12 * 13];    // [k][l]
    __shared__ float4 row0[64], col0[64], row1[32], col1[32], row2[12], col2[12];
    __shared__ float mxs[3];

    if (tid < 64) col0[tid].x = sc0[((size_t)g * 8 + h) * 64 + tid];
    else if (tid < 128) row0[tid - 64].x = sc0[((size_t)g * 8 + 4 + h) * 64 + (tid - 64)];
    else if (tid < 160) col1[tid - 128].x = sc1[((size_t)g * 8 + h) * 32 + (tid - 128)];
    else if (tid < 192) row1[tid - 160].x = sc1[((size_t)g * 8 + 4 + h) * 32 + (tid - 160)];
    else if (tid < 204) col2[tid - 192].x = sc2[((size_t)g * 8 + h) * 12 + (tid - 192)];
    else if (tid < 216) row2[tid - 204].x = sc2[((size_t)g * 8 + 4 + h) * 12 + (tid - 204)];
    __syncthreads();

    if (tid < 64) {
        float mx = row0[0].x;
        for (int i = 1; i < 64; ++i) mx = fmaxf(mx, row0[i].x);
        if (tid == 0) mxs[0] = mx;
        float a = row0[tid].x;
        row0[tid] = make_float4(a, __expf(a - mx), __expf(0.2f * (a - mx)), 0.f);
    } else if (tid < 96) {
        float mx = row1[0].x;
        for (int k = 1; k < 32; ++k) mx = fmaxf(mx, row1[k].x);
        if (tid == 64) mxs[1] = mx;
        int k = tid - 64;
        float a = row1[k].x;
        row1[k] = make_float4(a, __expf(a - mx), __expf(0.2f * (a - mx)), 0.f);
    } else if (tid < 108) {
        float mx = row2[0].x;
        for (int k = 1; k < 12; ++k) mx = fmaxf(mx, row2[k].x);
        if (tid == 96) mxs[2] = mx;
        int k = tid - 96;
        float a = row2[k].x;
        row2[k] = make_float4(a, __expf(a - mx), __expf(0.2f * (a - mx)), 0.f);
    }
    __syncthreads();

    if (tid < 64) {
        float a = col0[tid].x, mx = mxs[0];
        float mj = leaky(a + mx);
        float Em = __expf(a + mx - mj);
        float Fm = __expf(0.2f * (a + mx) - mj);
        float S1 = 0.f, S2 = 0.f;
        for (int i = 0; i < 64; ++i) {
            float4 r = row0[i];
            bool c = (a + r.x >= 0.f);
            S1 += c ? r.y : 0.f;
            S2 += c ? 0.f : r.z;
        }
        float iv = 1.f / (Em * S1 + Fm * S2);
        col0[tid] = make_float4(a, Em * iv, Fm * iv, 0.f);
    } else if (tid < 96) {
        int l = tid - 64;
        float a = col1[l].x, mx = mxs[1];
        float mj = leaky(a + mx);
        float E = __expf(a + mx - mj);
        float F = __expf(0.2f * (a + mx) - mj);
        float S1 = 0.f, S2 = 0.f;
        for (int k = 0; k < 32; ++k) {
            float4 r = row1[k];
            bool c = (a + r.x >= 0.f);
            S1 += c ? r.y : 0.f;
            S2 += c ? 0.f : r.z;
        }
        float iv = 1.f / (E * S1 + F * S2);
        col1[l] = make_float4(a, E * iv, F * iv, 0.f);
    } else if (tid < 108) {
        int l = tid - 96;
        float a = col2[l].x, mx = mxs[2];
        float mj = leaky(a + mx);
        float E = __expf(a + mx - mj);
        float F = __expf(0.2f * (a + mx) - mj);
        float S1 = 0.f, S2 = 0.f;
        for (int k = 0; k < 12; ++k) {
            float4 r = row2[k];
            bool c = (a + r.x >= 0.f);
            S1 += c ? r.y : 0.f;
            S2 += c ? 0.f : r.z;
        }
        float iv = 1.f / (E * S1 + F * S2);
        col2[l] = make_float4(a, E * iv, F * iv, 0.f);
    }
    __syncthreads();

    #pragma unroll
    for (int q = 0; q < 4; ++q) {
        int idx = q * 256 + tid;
        int k = idx >> 5, l = idx & 31;
        float4 rk = row1[k];
        float4 cl = col1[l];
        A1[k * 36 + l] = (cl.x + rk.x >= 0.f) ? cl.y * rk.y : cl.z * rk.z;
    }
    if (tid < 144) {
        int k = tid / 12, l = tid - k * 12;
        float4 rk = row2[k];
        float4 cl = col2[l];
        A2[k * 13 + l] = (cl.x + rk.x >= 0.f) ? cl.y * rk.y : cl.z * rk.z;
    }
    __syncthreads();

    {
        const int j = tid & 63, l0 = (tid >> 6) * 8;
        const float* ljrow = L1 + ((size_t)h * 64 + j) * 32;
        float acc8[8] = {};
        for (int k = 0; k < 32; ++k) {
            float lk = ljrow[k];
            float4 a4a = *(const float4*)&A1[k * 36 + l0];
            float4 a4b = *(const float4*)&A1[k * 36 + l0 + 4];
            acc8[0] += lk * a4a.x; acc8[1] += lk * a4a.y;
            acc8[2] += lk * a4a.z; acc8[3] += lk * a4a.w;
            acc8[4] += lk * a4b.x; acc8[5] += lk * a4b.y;
            acc8[6] += lk * a4b.z; acc8[7] += lk * a4b.w;
        }
        #pragma unroll
        for (int lo = 0; lo < 8; ++lo) t1T[(l0 + lo) * 64 + j] = acc8[lo];
        const int lb = (tid >> 6) * 3;
        float lj2[12];
        const float4* lp2 = (const float4*)(L2 + ((size_t)h * 64 + j) * 12);
        #pragma unroll
        for (int q = 0; q < 3; ++q) {
            float4 v = lp2[q];
            lj2[q * 4] = v.x; lj2[q * 4 + 1] = v.y;
            lj2[q * 4 + 2] = v.z; lj2[q * 4 + 3] = v.w;
        }
        #pragma unroll
        for (int lo = 0; lo < 3; ++lo) {
            int l = lb + lo;
            float acc = 0.f;
            #pragma unroll
            for (int k = 0; k < 12; ++k) acc += lj2[k] * A2[k * 13 + l];
            t2T[l * 64 + j] = acc;
        }
    }
    __syncthreads();

    const int i0 = (tid >> 4) << 2, m0 = (tid & 15) << 2;
    float acc[4][4];
    {
        float4 cm[4] = {col0[m0], col0[m0 + 1], col0[m0 + 2], col0[m0 + 3]};
        float4 ri[4] = {row0[i0], row0[i0 + 1], row0[i0 + 2], row0[i0 + 3]};
        #pragma unroll
        for (int r = 0; r < 4; ++r)
            #pragma unroll
            for (int c = 0; c < 4; ++c)
                acc[r][c] = (cm[c].x + ri[r].x >= 0.f) ? cm[c].y * ri[r].y
                                                       : cm[c].z * ri[r].z;
    }
    const float* r1b = R1 + (size_t)h * 2048;
    #pragma unroll 8
    for (int l = 0; l < 32; ++l) {
        float4 t4 = *(const float4*)&t1T[l * 64 + i0];
        float4 r4 = *(const float4*)(r1b + l * 64 + m0);
        float tv[4] = {t4.x, t4.y, t4.z, t4.w};
        float rv[4] = {r4.x, r4.y, r4.z, r4.w};
        #pragma unroll
        for (int r = 0; r < 4; ++r)
            #pragma unroll
            for (int c = 0; c < 4; ++c) acc[r][c] += tv[r] * rv[c];
    }
    const float* r2b = R2 + (size_t)h * 768;
    #pragma unroll 4
    for (int l = 0; l < 12; ++l) {
        float4 t4 = *(const float4*)&t2T[l * 64 + i0];
        float4 r4 = *(const float4*)(r2b + l * 64 + m0);
        float tv[4] = {t4.x, t4.y, t4.z, t4.w};
        float rv[4] = {r4.x, r4.y, r4.z, r4.w};
        #pragma unroll
        for (int r = 0; r < 4; ++r)
            #pragma unroll
            for (int c = 0; c < 4; ++c) acc[r][c] += tv[r] * rv[c];
    }
    float* op = out + ((size_t)g * 4 + h) * 4096;
    #pragma unroll
    for (int r = 0; r < 4; ++r)
        *(float4*)&op[(i0 + r) * 64 + m0] =
            make_float4(acc[r][0], acc[r][1], acc[r][2], acc[r][3]);
}

// ---------------------------------------------------------------------------
// Fused GAT0 + fuse, spatial, rank-1 factored softmax (unchanged).
// ---------------------------------------------------------------------------
__global__ __launch_bounds__(256, 5) void gatfuse_s(
    const float* __restrict__ sc0,  // (4096,8,25)
    const float* __restrict__ sc1,  // (4096,8,12)
    const float* __restrict__ sc2,  // (4096,8,5)
    const float* __restrict__ L1,   // (4,25,12)
    const float* __restrict__ R1,   // (4,12,25)
    const float* __restrict__ L2,   // (4,25,5)
    const float* __restrict__ R2,   // (4,5,25)
    float* __restrict__ out)        // (4096,4,25,25)
{
    const int g = blockIdx.x;
    const int tid = threadIdx.x;
    const int h = tid >> 6, t = tid & 63;
    __shared__ float4 row0[4][25], col0[4][25];
    __shared__ float4 row1[4][12], col1[4][12];
    __shared__ float4 row2[4][5], col2[4][5];
    __shared__ float A1[4][12 * 13];   // [k][l]
    __shared__ float A2[4][5 * 6];     // [k][l]
    __shared__ float t1l[4][25 * 16];  // [i][l] pad zero
    __shared__ float t2l[4][25 * 8];   // [i][l] pad zero
    __shared__ float r1T[4][25 * 16];  // [m][l] pad zero
    __shared__ float r2T[4][25 * 8];   // [m][l] pad zero
    __shared__ float mxs[4][3];

    for (int p = t; p < 84; p += 64) {
        if (p < 25)      col0[h][p].x      = sc0[((size_t)g * 8 + h) * 25 + p];
        else if (p < 50) row0[h][p - 25].x = sc0[((size_t)g * 8 + 4 + h) * 25 + (p - 25)];
        else if (p < 62) col1[h][p - 50].x = sc1[((size_t)g * 8 + h) * 12 + (p - 50)];
        else if (p < 74) row1[h][p - 62].x = sc1[((size_t)g * 8 + 4 + h) * 12 + (p - 62)];
        else if (p < 79) col2[h][p - 74].x = sc2[((size_t)g * 8 + h) * 5 + (p - 74)];
        else             row2[h][p - 79].x = sc2[((size_t)g * 8 + 4 + h) * 5 + (p - 79)];
    }
    for (int idx = t; idx < 400; idx += 64) {
        int m = idx >> 4, l = idx & 15;
        r1T[h][idx] = (l < 12) ? R1[h * 300 + l * 25 + m] : 0.f;
    }
    for (int idx = t; idx < 200; idx += 64) {
        int m = idx >> 3, l = idx & 7;
        r2T[h][idx] = (l < 5) ? R2[h * 125 + l * 25 + m] : 0.f;
    }
    __syncthreads();

    if (t < 25) {
        float mx = row0[h][0].x;
        for (int i = 1; i < 25; ++i) mx = fmaxf(mx, row0[h][i].x);
        if (t == 0) mxs[h][0] = mx;
        float a = row0[h][t].x;
        row0[h][t] = make_float4(a, __expf(a - mx), __expf(0.2f * (a - mx)), 0.f);
    } else if (t >= 32 && t < 44) {
        float mx = row1[h][0].x;
        for (int k = 1; k < 12; ++k) mx = fmaxf(mx, row1[h][k].x);
        if (t == 32) mxs[h][1] = mx;
        int k = t - 32;
        float a = row1[h][k].x;
        row1[h][k] = make_float4(a, __expf(a - mx), __expf(0.2f * (a - mx)), 0.f);
    } else if (t >= 48 && t < 53) {
        float mx = row2[h][0].x;
        for (int k = 1; k < 5; ++k) mx = fmaxf(mx, row2[h][k].x);
        if (t == 48) mxs[h][2] = mx;
        int k = t - 48;
        float a = row2[h][k].x;
        row2[h][k] = make_float4(a, __expf(a - mx), __expf(0.2f * (a - mx)), 0.f);
    }
    __syncthreads();

    if (t < 25) {
        float a = col0[h][t].x, mx = mxs[h][0];
        float mj = leaky(a + mx);
        float E = __expf(a + mx - mj);
        float F = __expf(0.2f * (a + mx) - mj);
        float S1 = 0.f, S2 = 0.f;
        for (int i = 0; i < 25; ++i) {
            float4 r = row0[h][i];
            bool c = (a + r.x >= 0.f);
            S1 += c ? r.y : 0.f;
            S2 += c ? 0.f : r.z;
        }
        float iv = 1.f / (E * S1 + F * S2);
        col0[h][t] = make_float4(a, E * iv, F * iv, 0.f);
    } else if (t >= 32 && t < 44) {
        int l = t - 32;
        float a = col1[h][l].x, mx = mxs[h][1];
        float mj = leaky(a + mx);
        float E = __expf(a + mx - mj);
        float F = __expf(0.2f * (a + mx) - mj);
        float S1 = 0.f, S2 = 0.f;
        for (int k = 0; k < 12; ++k) {
            float4 r = row1[h][k];
            bool c = (a + r.x >= 0.f);
            S1 += c ? r.y : 0.f;
            S2 += c ? 0.f : r.z;
        }
        float iv = 1.f / (E * S1 + F * S2);
        col1[h][l] = make_float4(a, E * iv, F * iv, 0.f);
    } else if (t >= 48 && t < 53) {
        int l = t - 48;
        float a = col2[h][l].x, mx = mxs[h][2];
        float mj = leaky(a + mx);
        float E = __expf(a + mx - mj);
        float F = __expf(0.2f * (a + mx) - mj);
        float S1 = 0.f, S2 = 0.f;
        for (int k = 0; k < 5; ++k) {
            float4 r = row2[h][k];
            bool c = (a + r.x >= 0.f);
            S1 += c ? r.y : 0.f;
            S2 += c ? 0.f : r.z;
        }
        float iv = 1.f / (E * S1 + F * S2);
        col2[h][l] = make_float4(a, E * iv, F * iv, 0.f);
    }
    __syncthreads();

    for (int p = t; p < 144; p += 64) {
        int k = p / 12, l = p - k * 12;
        float4 rk = row1[h][k];
        float4 cl = col1[h][l];
        A1[h][k * 13 + l] = (cl.x + rk.x >= 0.f) ? cl.y * rk.y : cl.z * rk.z;
    }
    if (t < 25) {
        int k = t / 5, l = t - (t / 5) * 5;
        float4 rk = row2[h][k];
        float4 cl = col2[h][l];
        A2[h][k * 6 + l] = (cl.x + rk.x >= 0.f) ? cl.y * rk.y : cl.z * rk.z;
    }
    __syncthreads();

    if (t < 25) {
        float lj[12];
        const float4* lp = (const float4*)(L1 + ((size_t)h * 25 + t) * 12);
        #pragma unroll
        for (int q = 0; q < 3; ++q) {
            float4 v = lp[q];
            lj[q * 4] = v.x; lj[q * 4 + 1] = v.y; lj[q * 4 + 2] = v.z; lj[q * 4 + 3] = v.w;
        }
        #pragma unroll
        for (int l = 0; l < 12; ++l) {
            float acc = 0.f;
            #pragma unroll
            for (int k = 0; k < 12; ++k) acc += lj[k] * A1[h][k * 13 + l];
            t1l[h][t * 16 + l] = acc;
        }
        #pragma unroll
        for (int l = 12; l < 16; ++l) t1l[h][t * 16 + l] = 0.f;
        float lj2[5];
        const float* lp2 = L2 + ((size_t)h * 25 + t) * 5;
        #pragma unroll
        for (int k = 0; k < 5; ++k) lj2[k] = lp2[k];
        #pragma unroll
        for (int l = 0; l < 5; ++l) {
            float acc = 0.f;
            #pragma unroll
            for (int k = 0; k < 5; ++k) acc += lj2[k] * A2[h][k * 6 + l];
            t2l[h][t * 8 + l] = acc;
        }
        #pragma unroll
        for (int l = 5; l < 8; ++l) t2l[h][t * 8 + l] = 0.f;
    }
    __syncthreads();

    float* op = out + ((size_t)g * 4 + h) * 625;
    for (int idx = t; idx < 625; idx += 64) {
        int i = idx / 25, m = idx - i * 25;
        float4 cm = col0[h][m];
        float4 ri = row0[h][i];
        float val = (cm.x + ri.x >= 0.f) ? cm.y * ri.y : cm.z * ri.z;
        const float* t1r = &t1l[h][i * 16];
        const float* r1c = &r1T[h][m * 16];
        #pragma unroll
        for (int q = 0; q < 4; ++q) {
            float4 tv = *(const float4*)&t1r[q * 4];
            float4 rv = *(const float4*)&r1c[q * 4];
            val += tv.x * rv.x + tv.y * rv.y + tv.z * rv.z + tv.w * rv.w;
        }
        const float* t2r = &t2l[h][i * 8];
        const float* r2c = &r2T[h][m * 8];
        #pragma unroll
        for (int q = 0; q < 2; ++q) {
            float4 tv = *(const float4*)&t2r[q * 4];
            float4 rv = *(const float4*)&r2c[q * 4];
            val += tv.x * rv.x + tv.y * rv.y + tv.z * rv.z + tv.w * rv.w;
        }
        op[idx] = val;
    }
}

// ---------------------------------------------------------------------------
extern "C" void kernel_launch(void* const* d_in, const int* in_sizes, int n_in,
                              void* d_out, int out_size, void* d_ws, size_t ws_size,
                              hipStream_t stream) {
    const float* src    = (const float*)d_in[0];
    const float* lin    = (const float*)d_in[1];
    const float* asrc   = (const float*)d_in[2];
    const float* adst   = (const float*)d_in[3];
    const float* sp0_W1 = (const float*)d_in[4];
    const float* sp0_b1 = (const float*)d_in[5];
    const float* sp0_W2 = (const float*)d_in[6];
    const float* sp0_b2 = (const float*)d_in[7];
    const float* sp1_W1 = (const float*)d_in[8];
    const float* sp1_b1 = (const float*)d_in[9];
    const float* sp1_W2 = (const float*)d_in[10];
    const float* sp1_b2 = (const float*)d_in[11];
    const float* tp0_W1 = (const float*)d_in[12];
    const float* tp0_b1 = (const float*)d_in[13];
    const float* tp0_W2 = (const float*)d_in[14];
    const float* tp0_b2 = (const float*)d_in[15];
    const float* tp1_W1 = (const float*)d_in[16];
    const float* tp1_b1 = (const float*)d_in[17];
    const float* tp1_W2 = (const float*)d_in[18];
    const float* tp1_b2 = (const float*)d_in[19];
    const float* sl0    = (const float*)d_in[20];
    const float* sr0    = (const float*)d_in[21];
    const float* sl1    = (const float*)d_in[22];
    const float* sr1    = (const float*)d_in[23];
    const float* tl0    = (const float*)d_in[24];
    const float* tr0    = (const float*)d_in[25];
    const float* tl1    = (const float*)d_in[26];
    const float* tr1    = (const float*)d_in[27];

    float* out_s = (float*)d_out;                 // (4096,4,25,25)
    float* out_t = out_s + 10240000;              // (1600,4,64,64)

    float* ws   = (float*)d_ws;
    float* wbuf = ws;                             // 3072 used (reserve 4096)
    float* wT   = ws + 4096;                      // 20480

    float* sp0_W1T = wT;
    float* sp1_W1T = wT + 4096;
    float* tp0_W1T = wT + 8192;
    float* tp1_W1T = wT + 12288;
    float* sp0_W2T = wT + 16384;                  // 64x12
    float* sp1_W2T = wT + 17152;                  // 64x8
    float* tp0_W2T = wT + 17664;                  // 64x32
    float* tp1_W2T = wT + 19712;                  // 64x12

    // branches run sequentially -> buffers aliased across branches
    float* xbuf  = ws + 24576;                    // max(xs, xt)   = 6,553,600
    float* x1buf = xbuf + 6553600;                // max(xs1, xt1) = 3,276,800
    float* sc0b  = x1buf + 3276800;               // max sc0       = 819,200
    float* sc1b  = sc0b + 819200;                 // max sc1       = 409,600
    float* sc2b  = sc1b + 409600;                 // max sc2       = 163,840

    wprep_kernel<<<6, 256, 0, stream>>>(lin, asrc, adst, wbuf);
    wtrans_kernel<<<80, 256, 0, stream>>>(sp0_W1, sp1_W1, tp0_W1, tp1_W1,
                                          sp0_W2, sp1_W2, tp0_W2, tp1_W2, wT);

    // ---- spatial branch ----
    xs_kernel<<<4096, 256, 0, stream>>>(src, wbuf + 0 * 512, xbuf, sc0b);
    pool_kernel<25, 25, 12, 12, 1><<<4096, 256, 0, stream>>>(
        xbuf, sp0_W1T, sp0_b1, sp0_W2T, sp0_b2, wbuf + 1 * 512, x1buf, sc1b);
    pool_kernel<12, 12, 5, 8, 0><<<4096, 256, 0, stream>>>(
        x1buf, sp1_W1T, sp1_b1, sp1_W2T, sp1_b2, wbuf + 2 * 512, nullptr, sc2b);
    gatfuse_s<<<4096, 256, 0, stream>>>(sc0b, sc1b, sc2b, sl0, sr0, sl1, sr1, out_s);

    // ---- temporal branch ----
    xt_kernel<<<1600, 256, 0, stream>>>(src, wbuf + 3 * 512, xbuf, sc0b);
    pool_kernel<64, 32, 32, 32, 1><<<1600, 256, 0, stream>>>(
        xbuf, tp0_W1T, tp0_b1, tp0_W2T, tp0_b2, wbuf + 4 * 512, x1buf, sc1b);
    pool_kernel<32, 32, 12, 12, 0><<<1600, 256, 0, stream>>>(
        x1buf, tp1_W1T, tp1_b1, tp1_W2T, tp1_b2, wbuf + 5 * 512, nullptr, sc2b);
    gatfuse_t<<<6400, 256, 0, stream>>>(sc0b, sc1b, sc2b, tl0, tr0, tl1, tr1, out_t);
}

// Round 8
// 419.247 us; speedup vs baseline: 1.1053x; 1.1053x over previous
//
#include <hip/hip_runtime.h>

#define DEVINL __device__ __forceinline__

DEVINL float leaky(float v) { return v >= 0.f ? v : 0.2f * v; }

// ---------------------------------------------------------------------------
// Precompute per-level head projection vectors.
// ---------------------------------------------------------------------------
__global__ void wprep_kernel(const float* __restrict__ lin,   // (6,64,64)
                             const float* __restrict__ asrc,  // (6,4,16)
                             const float* __restrict__ adst,  // (6,4,16)
                             float* __restrict__ w_out) {     // (6,2,4,64)
    int idx = blockIdx.x * blockDim.x + threadIdx.x;
    if (idx >= 6 * 4 * 64) return;
    int c = idx & 63;
    int h = (idx >> 6) & 3;
    int k = idx >> 8;
    const float* L = lin + k * 64 * 64;
    float s1 = 0.f, s2 = 0.f;
    for (int e = 0; e < 16; ++e) {
        float w = L[(h * 16 + e) * 64 + c];
        s1 += w * asrc[(k * 4 + h) * 16 + e];
        s2 += w * adst[(k * 4 + h) * 16 + e];
    }
    w_out[(k * 2 + 0) * 256 + h * 64 + c] = s1;
    w_out[(k * 2 + 1) * 256 + h * 64 + c] = s2;
}

// ---------------------------------------------------------------------------
// Transpose pool weights once.
// ---------------------------------------------------------------------------
__global__ void wtrans_kernel(const float* __restrict__ s0, const float* __restrict__ s1,
                              const float* __restrict__ t0, const float* __restrict__ t1,
                              const float* __restrict__ s0w2, const float* __restrict__ s1w2,
                              const float* __restrict__ t0w2, const float* __restrict__ t1w2,
                              float* __restrict__ o) {
    int idx = blockIdx.x * 256 + threadIdx.x;
    if (idx < 16384) {
        int m = idx >> 12, r = idx & 4095, c = r >> 6, d = r & 63;
        const float* src = (m == 0) ? s0 : (m == 1) ? s1 : (m == 2) ? t0 : t1;
        o[idx] = src[d * 64 + c];
    } else if (idx < 16384 + 768) {
        int j = idx - 16384, c = j / 12, k = j - 12 * c;
        o[idx] = s0w2[k * 64 + c];
    } else if (idx < 17152 + 512) {
        int j = idx - 17152, c = j >> 3, k = j & 7;
        o[idx] = (k < 5) ? s1w2[k * 64 + c] : 0.f;
    } else if (idx < 17664 + 2048) {
        int j = idx - 17664, c = j >> 5, k = j & 31;
        o[idx] = t0w2[k * 64 + c];
    } else if (idx < 19712 + 768) {
        int j = idx - 19712, c = j / 12, k = j - 12 * c;
        o[idx] = t1w2[k * 64 + c];
    }
}

// ---------------------------------------------------------------------------
// Transposes: src (B=64, C=64, T=64, J=25)  [round-4 versions]
// ---------------------------------------------------------------------------
__global__ void xs_kernel(const float* __restrict__ src, float* __restrict__ xs) {
    int g = blockIdx.x;             // b*64 + t
    int b = g >> 6, t = g & 63;
    __shared__ float tile[64][26];  // [c][j]
    const float* sp = src + b * 102400 + t * 25;
    for (int idx = threadIdx.x; idx < 64 * 25; idx += blockDim.x) {
        int c = idx / 25, j = idx - c * 25;
        tile[c][j] = sp[c * 1600 + j];
    }
    __syncthreads();
    float* op = xs + g * 25 * 64;
    for (int idx = threadIdx.x; idx < 25 * 64; idx += blockDim.x) {
        int j = idx >> 6, c = idx & 63;
        op[idx] = tile[c][j];
    }
}

__global__ void xt_kernel(const float* __restrict__ src, float* __restrict__ xt) {
    int g = blockIdx.x;             // b*25 + j
    int b = g / 25, j = g - b * 25;
    __shared__ float tile[64][65];  // [c][t]
    const float* sp = src + b * 102400 + j;
    for (int idx = threadIdx.x; idx < 64 * 64; idx += blockDim.x) {
        int c = idx >> 6, t = idx & 63;
        tile[c][t] = sp[c * 1600 + t * 25];
    }
    __syncthreads();
    float* op = xt + g * 64 * 64;
    for (int idx = threadIdx.x; idx < 64 * 64; idx += blockDim.x) {
        int t = idx >> 6, c = idx & 63;
        op[idx] = tile[c][t];
    }
}

// ---------------------------------------------------------------------------
// GAT attention (intermediate levels): rank-1 factored softmax, row-major
// coalesced writes. att[g][h][i][j] = (a1[j]+a2[i]>=0)? cE[j]*rE[i] : cF[j]*rF[i]
// ---------------------------------------------------------------------------
template <int N>
__global__ __launch_bounds__(256) void gat_kernel(
    const float* __restrict__ x,  // (G,N,64)
    const float* __restrict__ w,  // [2][4][64] (src, dst)
    float* __restrict__ att) {    // (G,4,N,N)
    int g = blockIdx.x;
    const int tid = threadIdx.x;
    __shared__ float xlT[64][N + 1];  // [c][n]
    __shared__ float wl[512];
    __shared__ float a1s[4 * N], a2s[4 * N];
    __shared__ float rE[4 * N], rF[4 * N], cE[4 * N], cF[4 * N];
    __shared__ float mxs[4];
    const float* xp = x + (size_t)g * N * 64;
    for (int idx = tid; idx < N * 64; idx += 256) {
        int n = idx >> 6, c = idx & 63;
        xlT[c][n] = xp[idx];
    }
    for (int idx = tid; idx < 512; idx += 256) wl[idx] = w[idx];
    __syncthreads();
    for (int idx = tid; idx < 8 * N; idx += 256) {
        int n = idx % N;
        int hh = (idx / N) & 3;
        int sd = idx / (4 * N);
        const float* wp = wl + sd * 256 + hh * 64;
        float acc = 0.f;
        #pragma unroll 8
        for (int c = 0; c < 64; ++c) acc += xlT[c][n] * wp[c];
        (sd == 0 ? a1s : a2s)[hh * N + n] = acc;
    }
    __syncthreads();
    if (tid < 4) {
        float m = -1e30f;
        for (int i = 0; i < N; ++i) m = fmaxf(m, a2s[tid * N + i]);
        mxs[tid] = m;
    }
    __syncthreads();
    // rows: exp(a2-mx), exp(0.2(a2-mx))
    for (int idx = tid; idx < 4 * N; idx += 256) {
        int hh = idx / N;
        float d = a2s[idx] - mxs[hh];
        rE[idx] = __expf(d);
        rF[idx] = __expf(0.2f * d);
    }
    __syncthreads();
    // cols: E*iv, F*iv with masked sums
    for (int idx = tid; idx < 4 * N; idx += 256) {
        int hh = idx / N;
        float a = a1s[idx], mx = mxs[hh];
        float mj = leaky(a + mx);
        float E = __expf(a + mx - mj);
        float F = __expf(0.2f * (a + mx) - mj);
        float S1 = 0.f, S2 = 0.f;
        for (int i = 0; i < N; ++i) {
            bool c = (a + a2s[hh * N + i] >= 0.f);
            S1 += c ? rE[hh * N + i] : 0.f;
            S2 += c ? 0.f : rF[hh * N + i];
        }
        float iv = 1.f / (E * S1 + F * S2);
        cE[idx] = E * iv;
        cF[idx] = F * iv;
    }
    __syncthreads();
    float* ob = att + (size_t)g * 4 * N * N;
    if constexpr ((N % 4) == 0) {
        constexpr int NF4 = N / 4;
        for (int idx = tid; idx < 4 * N * NF4; idx += 256) {
            int row = idx / NF4;           // h*N + i
            int j0 = (idx - row * NF4) * 4;
            int hh = row / N;
            float4 q1 = *(const float4*)&a1s[(row / N) * N + j0];
            float4 qE = *(const float4*)&cE[hh * N + j0];
            float4 qF = *(const float4*)&cF[hh * N + j0];
            float a2i = a2s[row];
            float rEi = rE[row], rFi = rF[row];
            float a1v[4] = {q1.x, q1.y, q1.z, q1.w};
            float ev[4] = {qE.x, qE.y, qE.z, qE.w};
            float fv[4] = {qF.x, qF.y, qF.z, qF.w};
            float r[4];
            #pragma unroll
            for (int c = 0; c < 4; ++c)
                r[c] = (a1v[c] + a2i >= 0.f) ? ev[c] * rEi : fv[c] * rFi;
            *(float4*)&ob[row * N + j0] = make_float4(r[0], r[1], r[2], r[3]);
        }
    } else {
        for (int idx = tid; idx < 4 * N * N; idx += 256) {
            int hh = idx / (N * N), rem = idx - hh * N * N;
            int i = rem / N, j = rem - i * N;
            bool cnd = (a1s[hh * N + j] + a2s[hh * N + i] >= 0.f);
            ob[idx] = cnd ? cE[hh * N + j] * rE[hh * N + i]
                          : cF[hh * N + j] * rF[hh * N + i];
        }
    }
}

// ---------------------------------------------------------------------------
// Diff-pool, register-tiled (round-4 version, measured good).
// ---------------------------------------------------------------------------
template <int N, int K, int KP>
__global__ __launch_bounds__(256, 3) void pool_kernel(
    const float* __restrict__ x,    // (G,N,64)
    const float* __restrict__ W1T,  // (64,64) [c][d]
    const float* __restrict__ b1,   // (64)
    const float* __restrict__ W2T,  // (64,KP) [d][k], pad cols zero
    const float* __restrict__ b2,   // (K)
    float* __restrict__ xo) {       // (G,K,64)
    constexpr int NP = (N + 3) & ~3;
    constexpr int LDN = NP + 1;
    __shared__ float xlT[64 * LDN];  // [c][n]
    __shared__ float yT[64 * LDN];   // [d][n]
    __shared__ float sT[KP * LDN];   // [k][n]
    const int g = blockIdx.x, tid = threadIdx.x;
    const float* xp = x + (size_t)g * N * 64;
    for (int i4 = tid; i4 < N * 16; i4 += 256) {
        int n = i4 >> 4, c0 = (i4 & 15) << 2;
        float4 v = ((const float4*)xp)[i4];
        xlT[(c0 + 0) * LDN + n] = v.x;
        xlT[(c0 + 1) * LDN + n] = v.y;
        xlT[(c0 + 2) * LDN + n] = v.z;
        xlT[(c0 + 3) * LDN + n] = v.w;
    }
    if constexpr (NP > N) {
        for (int i = tid; i < 64 * (NP - N); i += 256) {
            int c = i / (NP - N), n = N + i % (NP - N);
            xlT[c * LDN + n] = 0.f;
        }
    }
    __syncthreads();
    constexpr int T1 = (NP / 4) * 16;
    if (tid < T1) {
        int d0 = (tid & 15) << 2, n0 = (tid >> 4) << 2;
        float acc[4][4] = {};
        #pragma unroll 4
        for (int c = 0; c < 64; ++c) {
            float4 w4 = *(const float4*)(W1T + c * 64 + d0);
            float wv[4] = {w4.x, w4.y, w4.z, w4.w};
            float xv[4];
            #pragma unroll
            for (int r = 0; r < 4; ++r) xv[r] = xlT[c * LDN + n0 + r];
            #pragma unroll
            for (int r = 0; r < 4; ++r)
                #pragma unroll
                for (int cc = 0; cc < 4; ++cc) acc[r][cc] += xv[r] * wv[cc];
        }
        float4 b4 = *(const float4*)(b1 + d0);
        float bb[4] = {b4.x, b4.y, b4.z, b4.w};
        #pragma unroll
        for (int r = 0; r < 4; ++r)
            #pragma unroll
            for (int cc = 0; cc < 4; ++cc)
                yT[(d0 + cc) * LDN + n0 + r] = fmaxf(acc[r][cc] + bb[cc], 0.f);
    }
    __syncthreads();
    constexpr int KG4 = KP / 4;
    constexpr int T2 = (NP / 4) * KG4;
    if (tid < T2) {
        int k0 = (tid % KG4) << 2, n0 = (tid / KG4) << 2;
        float acc[4][4] = {};
        #pragma unroll 4
        for (int d = 0; d < 64; ++d) {
            float4 w4 = *(const float4*)(W2T + d * KP + k0);
            float wv[4] = {w4.x, w4.y, w4.z, w4.w};
            float yv[4];
            #pragma unroll
            for (int r = 0; r < 4; ++r) yv[r] = yT[d * LDN + n0 + r];
            #pragma unroll
            for (int r = 0; r < 4; ++r)
                #pragma unroll
                for (int cc = 0; cc < 4; ++cc) acc[r][cc] += yv[r] * wv[cc];
        }
        #pragma unroll
        for (int cc = 0; cc < 4; ++cc) {
            int k = k0 + cc;
            float bb = (k < K) ? b2[k] : 0.f;
            #pragma unroll
            for (int r = 0; r < 4; ++r)
                sT[k * LDN + n0 + r] = (k < K) ? (acc[r][cc] + bb) : -1e30f;
        }
    }
    __syncthreads();
    if (tid < NP) {
        float m = -1e30f;
        #pragma unroll
        for (int k = 0; k < KP; ++k) m = fmaxf(m, sT[k * LDN + tid]);
        float sum = 0.f;
        float e[KP];
        #pragma unroll
        for (int k = 0; k < KP; ++k) { e[k] = __expf(sT[k * LDN + tid] - m); sum += e[k]; }
        float inv = 1.f / sum;
        #pragma unroll
        for (int k = 0; k < KP; ++k) sT[k * LDN + tid] = e[k] * inv;
    }
    __syncthreads();
    constexpr int KG2 = (K + 1) / 2;
    constexpr int T3 = KG2 * 16;
    if (tid < T3) {
        int k0 = (tid % KG2) * 2, c0 = (tid / KG2) * 4;
        float acc0[4] = {}, acc1[4] = {};
        #pragma unroll 4
        for (int n = 0; n < N; ++n) {
            float sv0 = sT[k0 * LDN + n];
            float sv1 = sT[(k0 + 1) * LDN + n];
            float xv[4];
            #pragma unroll
            for (int j = 0; j < 4; ++j) xv[j] = xlT[(c0 + j) * LDN + n];
            #pragma unroll
            for (int j = 0; j < 4; ++j) { acc0[j] += sv0 * xv[j]; acc1[j] += sv1 * xv[j]; }
        }
        float* op = xo + (size_t)g * K * 64;
        *(float4*)&op[k0 * 64 + c0] = make_float4(acc0[0], acc0[1], acc0[2], acc0[3]);
        if (k0 + 1 < K)
            *(float4*)&op[(k0 + 1) * 64 + c0] = make_float4(acc1[0], acc1[1], acc1[2], acc1[3]);
    }
}

// ---------------------------------------------------------------------------
// Fused GAT0 + low-rank fuse, temporal. A1/A2 from global (materialized by
// gat_kernel); level-0 scores computed from x; rank-1 factored softmax.
// 18 KB LDS, stats/build overlapped across waves. Block=(g,h) XCD-swizzled.
// ---------------------------------------------------------------------------
__global__ __launch_bounds__(256, 8) void gatfuse_t(
    const float* __restrict__ x,    // (1600,64,64)
    const float* __restrict__ w,    // [2][4][64]
    const float* __restrict__ A1g,  // (1600,4,32,32)
    const float* __restrict__ L1,   // (4,64,32)
    const float* __restrict__ R1,   // (4,32,64)
    const float* __restrict__ A2g,  // (1600,4,12,12)
    const float* __restrict__ L2,   // (4,64,12)
    const float* __restrict__ R2,   // (4,12,64)
    float* __restrict__ out)        // (1600,4,64,64)
{
    const int bid = blockIdx.x;
    const int g = (bid & 7) | ((bid >> 5) << 3);   // 4 heads of one g -> same XCD
    const int h = (bid >> 3) & 3;
    const int tid = threadIdx.x;
    __shared__ float t1T[32 * 64];   // [l][j]
    __shared__ float t2T[12 * 64];   // [l][j]
    __shared__ float A1[32 * 36];    // [k][l], padded
    __shared__ float A2[12 * 13];    // [k][l]
    __shared__ float a01[64], a02[64];       // col (src), row (dst) scores
    __shared__ float rEs[64], rFs[64], cEs[64], cFs[64];

    // ---- phase 1: scores (waves 0-1, from global x) || stage A1/A2 (waves 2-3)
    if (tid < 128) {
        int t = tid & 63, sd = tid >> 6;
        const float4* xr = (const float4*)(x + (size_t)g * 4096 + t * 64);
        const float* wv = w + sd * 256 + h * 64;
        float acc = 0.f;
        #pragma unroll
        for (int q = 0; q < 16; ++q) {
            float4 xv = xr[q];
            float4 w4 = *(const float4*)(wv + q * 4);
            acc += xv.x * w4.x + xv.y * w4.y + xv.z * w4.z + xv.w * w4.w;
        }
        (sd == 0 ? a01 : a02)[t] = acc;
    } else {
        int u = tid - 128;
        const float* a1p = A1g + (size_t)(g * 4 + h) * 1024;
        #pragma unroll
        for (int q = 0; q < 8; ++q) {
            int idx = q * 128 + u;                 // = k*32 + l
            A1[(idx >> 5) * 36 + (idx & 31)] = a1p[idx];
        }
        const float* a2p = A2g + (size_t)(g * 4 + h) * 144;
        for (int idx = u; idx < 144; idx += 128) {
            int k = idx / 12, l = idx - k * 12;
            A2[k * 13 + l] = a2p[idx];
        }
    }
    __syncthreads();

    // ---- phase 2: wave 0 = row factors; waves 1-3 = t1T rows 8..31
    if (tid < 64) {
        float mx = a02[0];
        for (int i = 1; i < 64; ++i) mx = fmaxf(mx, a02[i]);
        float d = a02[tid] - mx;
        rEs[tid] = __expf(d);
        rFs[tid] = __expf(0.2f * d);
        cEs[tid] = mx;   // stash mx (overwritten in phase 3)
    } else {
        const int j = tid & 63, l0 = (tid >> 6) * 8;   // l0 = 8,16,24
        float lj[32];
        const float4* lp = (const float4*)(L1 + ((size_t)h * 64 + j) * 32);
        #pragma unroll
        for (int q = 0; q < 8; ++q) {
            float4 v = lp[q];
            lj[q * 4] = v.x; lj[q * 4 + 1] = v.y; lj[q * 4 + 2] = v.z; lj[q * 4 + 3] = v.w;
        }
        float acc8[8] = {};
        for (int k = 0; k < 32; ++k) {
            float lk = lj[k];
            float4 a4a = *(const float4*)&A1[k * 36 + l0];
            float4 a4b = *(const float4*)&A1[k * 36 + l0 + 4];
            acc8[0] += lk * a4a.x; acc8[1] += lk * a4a.y;
            acc8[2] += lk * a4a.z; acc8[3] += lk * a4a.w;
            acc8[4] += lk * a4b.x; acc8[5] += lk * a4b.y;
            acc8[6] += lk * a4b.z; acc8[7] += lk * a4b.w;
        }
        #pragma unroll
        for (int lo = 0; lo < 8; ++lo) t1T[(l0 + lo) * 64 + j] = acc8[lo];
    }
    __syncthreads();

    // ---- phase 3: wave0 = col factors; wave1 = t1T rows 0-7; waves 2-3 = t2T
    if (tid < 64) {
        float mx = cEs[tid];
        float a = a01[tid];
        float mj = leaky(a + mx);
        float E = __expf(a + mx - mj);
        float F = __expf(0.2f * (a + mx) - mj);
        float S1 = 0.f, S2 = 0.f;
        for (int i = 0; i < 64; ++i) {
            bool c = (a + a02[i] >= 0.f);
            S1 += c ? rEs[i] : 0.f;
            S2 += c ? 0.f : rFs[i];
        }
        float iv = 1.f / (E * S1 + F * S2);
        cEs[tid] = E * iv;
        cFs[tid] = F * iv;
    } else if (tid < 128) {
        const int j = tid & 63;
        float lj[32];
        const float4* lp = (const float4*)(L1 + ((size_t)h * 64 + j) * 32);
        #pragma unroll
        for (int q = 0; q < 8; ++q) {
            float4 v = lp[q];
            lj[q * 4] = v.x; lj[q * 4 + 1] = v.y; lj[q * 4 + 2] = v.z; lj[q * 4 + 3] = v.w;
        }
        float acc8[8] = {};
        for (int k = 0; k < 32; ++k) {
            float lk = lj[k];
            float4 a4a = *(const float4*)&A1[k * 36];
            float4 a4b = *(const float4*)&A1[k * 36 + 4];
            acc8[0] += lk * a4a.x; acc8[1] += lk * a4a.y;
            acc8[2] += lk * a4a.z; acc8[3] += lk * a4a.w;
            acc8[4] += lk * a4b.x; acc8[5] += lk * a4b.y;
            acc8[6] += lk * a4b.z; acc8[7] += lk * a4b.w;
        }
        #pragma unroll
        for (int lo = 0; lo < 8; ++lo) t1T[lo * 64 + j] = acc8[lo];
    } else {
        const int j = tid & 63, lb = ((tid >> 6) - 2) * 6;   // 0 or 6
        float lj2[12];
        const float4* lp2 = (const float4*)(L2 + ((size_t)h * 64 + j) * 12);
        #pragma unroll
        for (int q = 0; q < 3; ++q) {
            float4 v = lp2[q];
            lj2[q * 4] = v.x; lj2[q * 4 + 1] = v.y;
            lj2[q * 4 + 2] = v.z; lj2[q * 4 + 3] = v.w;
        }
        #pragma unroll
        for (int lo = 0; lo < 6; ++lo) {
            int l = lb + lo;
            float acc = 0.f;
            #pragma unroll
            for (int k = 0; k < 12; ++k) acc += lj2[k] * A2[k * 13 + l];
            t2T[l * 64 + j] = acc;
        }
    }
    __syncthreads();

    // ---- main 4x4 register-tiled output
    const int i0 = (tid >> 4) << 2, m0 = (tid & 15) << 2;
    float acc[4][4];
    {
        float4 qa1 = *(const float4*)&a01[m0];
        float4 qcE = *(const float4*)&cEs[m0];
        float4 qcF = *(const float4*)&cFs[m0];
        float4 qa2 = *(const float4*)&a02[i0];
        float4 qrE = *(const float4*)&rEs[i0];
        float4 qrF = *(const float4*)&rFs[i0];
        float a1v[4] = {qa1.x, qa1.y, qa1.z, qa1.w};
        float ev[4] = {qcE.x, qcE.y, qcE.z, qcE.w};
        float fv[4] = {qcF.x, qcF.y, qcF.z, qcF.w};
        float a2v[4] = {qa2.x, qa2.y, qa2.z, qa2.w};
        float rev[4] = {qrE.x, qrE.y, qrE.z, qrE.w};
        float rfv[4] = {qrF.x, qrF.y, qrF.z, qrF.w};
        #pragma unroll
        for (int r = 0; r < 4; ++r)
            #pragma unroll
            for (int c = 0; c < 4; ++c)
                acc[r][c] = (a1v[c] + a2v[r] >= 0.f) ? ev[c] * rev[r]
                                                     : fv[c] * rfv[r];
    }
    const float* r1b = R1 + (size_t)h * 2048;
    #pragma unroll 8
    for (int l = 0; l < 32; ++l) {
        float4 t4 = *(const float4*)&t1T[l * 64 + i0];
        float4 r4 = *(const float4*)(r1b + l * 64 + m0);
        float tv[4] = {t4.x, t4.y, t4.z, t4.w};
        float rv[4] = {r4.x, r4.y, r4.z, r4.w};
        #pragma unroll
        for (int r = 0; r < 4; ++r)
            #pragma unroll
            for (int c = 0; c < 4; ++c) acc[r][c] += tv[r] * rv[c];
    }
    const float* r2b = R2 + (size_t)h * 768;
    #pragma unroll 4
    for (int l = 0; l < 12; ++l) {
        float4 t4 = *(const float4*)&t2T[l * 64 + i0];
        float4 r4 = *(const float4*)(r2b + l * 64 + m0);
        float tv[4] = {t4.x, t4.y, t4.z, t4.w};
        float rv[4] = {r4.x, r4.y, r4.z, r4.w};
        #pragma unroll
        for (int r = 0; r < 4; ++r)
            #pragma unroll
            for (int c = 0; c < 4; ++c) acc[r][c] += tv[r] * rv[c];
    }
    float* op = out + ((size_t)g * 4 + h) * 4096;
    #pragma unroll
    for (int r = 0; r < 4; ++r)
        *(float4*)&op[(i0 + r) * 64 + m0] =
            make_float4(acc[r][0], acc[r][1], acc[r][2], acc[r][3]);
}

// ---------------------------------------------------------------------------
// Fused GAT0 + fuse, spatial. A1/A2 from global; scores from xs; rank-1.
// Block = g, head = tid>>6.
// ---------------------------------------------------------------------------
__global__ __launch_bounds__(256, 5) void gatfuse_s(
    const float* __restrict__ x,    // (4096,25,64)
    const float* __restrict__ w,    // [2][4][64]
    const float* __restrict__ A1g,  // (4096,4,12,12)
    const float* __restrict__ L1,   // (4,25,12)
    const float* __restrict__ R1,   // (4,12,25)
    const float* __restrict__ A2g,  // (4096,4,5,5)
    const float* __restrict__ L2,   // (4,25,5)
    const float* __restrict__ R2,   // (4,5,25)
    float* __restrict__ out)        // (4096,4,25,25)
{
    const int g = blockIdx.x;
    const int tid = threadIdx.x;
    const int h = tid >> 6, t = tid & 63;
    __shared__ float xl[25 * 68];
    __shared__ float A1[4][12 * 13];   // [k][l]
    __shared__ float A2[4][5 * 6];     // [k][l]
    __shared__ float t1l[4][25 * 16];  // [i][l] pad zero
    __shared__ float t2l[4][25 * 8];   // [i][l] pad zero
    __shared__ float r1T[4][25 * 16];  // [m][l] pad zero
    __shared__ float r2T[4][25 * 8];   // [m][l] pad zero
    __shared__ float a01[4][25], a02[4][25];
    __shared__ float rE[4][25], rF[4][25], cE[4][25], cF[4][25];
    __shared__ float mxs[4];

    // ---- stage xl, A1, A2, R tiles
    const float* xp = x + (size_t)g * 1600;
    for (int idx = tid; idx < 400; idx += 256) {
        int n = idx >> 4, c0 = (idx & 15) << 2;
        *(float4*)&xl[n * 68 + c0] = *(const float4*)(xp + n * 64 + c0);
    }
    const float* a1p = A1g + (size_t)(g * 4 + h) * 144;
    for (int idx = t; idx < 144; idx += 64) {
        int k = idx / 12, l = idx - k * 12;
        A1[h][k * 13 + l] = a1p[idx];
    }
    const float* a2p = A2g + (size_t)(g * 4 + h) * 25;
    if (t < 25) {
        int k = t / 5, l = t - (t / 5) * 5;
        A2[h][k * 6 + l] = a2p[t];
    }
    for (int idx = t; idx < 400; idx += 64) {
        int m = idx >> 4, l = idx & 15;
        r1T[h][idx] = (l < 12) ? R1[h * 300 + l * 25 + m] : 0.f;
    }
    for (int idx = t; idx < 200; idx += 64) {
        int m = idx >> 3, l = idx & 7;
        r2T[h][idx] = (l < 5) ? R2[h * 125 + l * 25 + m] : 0.f;
    }
    __syncthreads();

    // ---- scores (per head, t<25)
    if (t < 25) {
        const float* ws_ = w + h * 64;
        const float* wd_ = w + 256 + h * 64;
        const float* xr = &xl[t * 68];
        float s1 = 0.f, s2 = 0.f;
        #pragma unroll
        for (int c = 0; c < 64; c += 4) {
            float4 xv = *(const float4*)&xr[c];
            float4 w1 = *(const float4*)(ws_ + c);
            float4 w2 = *(const float4*)(wd_ + c);
            s1 += xv.x * w1.x + xv.y * w1.y + xv.z * w1.z + xv.w * w1.w;
            s2 += xv.x * w2.x + xv.y * w2.y + xv.z * w2.z + xv.w * w2.w;
        }
        a01[h][t] = s1;
        a02[h][t] = s2;
    }
    __syncthreads();

    // ---- rows (t<25) || t1l/t2l build (t in 32..56)
    if (t < 25) {
        float mx = a02[h][0];
        for (int i = 1; i < 25; ++i) mx = fmaxf(mx, a02[h][i]);
        if (t == 0) mxs[h] = mx;
        float d = a02[h][t] - mx;
        rE[h][t] = __expf(d);
        rF[h][t] = __expf(0.2f * d);
    } else if (t >= 32 && t < 57) {
        int i = t - 32;
        float lj[12];
        const float4* lp = (const float4*)(L1 + ((size_t)h * 25 + i) * 12);
        #pragma unroll
        for (int q = 0; q < 3; ++q) {
            float4 v = lp[q];
            lj[q * 4] = v.x; lj[q * 4 + 1] = v.y; lj[q * 4 + 2] = v.z; lj[q * 4 + 3] = v.w;
        }
        #pragma unroll
        for (int l = 0; l < 12; ++l) {
            float acc = 0.f;
            #pragma unroll
            for (int k = 0; k < 12; ++k) acc += lj[k] * A1[h][k * 13 + l];
            t1l[h][i * 16 + l] = acc;
        }
        #pragma unroll
        for (int l = 12; l < 16; ++l) t1l[h][i * 16 + l] = 0.f;
        float lj2[5];
        const float* lp2 = L2 + ((size_t)h * 25 + i) * 5;
        #pragma unroll
        for (int k = 0; k < 5; ++k) lj2[k] = lp2[k];
        #pragma unroll
        for (int l = 0; l < 5; ++l) {
            float acc = 0.f;
            #pragma unroll
            for (int k = 0; k < 5; ++k) acc += lj2[k] * A2[h][k * 6 + l];
            t2l[h][i * 8 + l] = acc;
        }
        #pragma unroll
        for (int l = 5; l < 8; ++l) t2l[h][i * 8 + l] = 0.f;
    }
    __syncthreads();

    // ---- cols
    if (t < 25) {
        float a = a01[h][t], mx = mxs[h];
        float mj = leaky(a + mx);
        float E = __expf(a + mx - mj);
        float F = __expf(0.2f * (a + mx) - mj);
        float S1 = 0.f, S2 = 0.f;
        for (int i = 0; i < 25; ++i) {
            bool c = (a + a02[h][i] >= 0.f);
            S1 += c ? rE[h][i] : 0.f;
            S2 += c ? 0.f : rF[h][i];
        }
        float iv = 1.f / (E * S1 + F * S2);
        cE[h][t] = E * iv;
        cF[h][t] = F * iv;
    }
    __syncthreads();

    // ---- output: 625 per head
    float* op = out + ((size_t)g * 4 + h) * 625;
    for (int idx = t; idx < 625; idx += 64) {
        int i = idx / 25, m = idx - i * 25;
        bool cnd = (a01[h][m] + a02[h][i] >= 0.f);
        float val = cnd ? cE[h][m] * rE[h][i] : cF[h][m] * rF[h][i];
        const float* t1r = &t1l[h][i * 16];
        const float* r1c = &r1T[h][m * 16];
        #pragma unroll
        for (int q = 0; q < 4; ++q) {
            float4 tv = *(const float4*)&t1r[q * 4];
            float4 rv = *(const float4*)&r1c[q * 4];
            val += tv.x * rv.x + tv.y * rv.y + tv.z * rv.z + tv.w * rv.w;
        }
        const float* t2r = &t2l[h][i * 8];
        const float* r2c = &r2T[h][m * 8];
        #pragma unroll
        for (int q = 0; q < 2; ++q) {
            float4 tv = *(const float4*)&t2r[q * 4];
            float4 rv = *(const float4*)&r2c[q * 4];
            val += tv.x * rv.x + tv.y * rv.y + tv.z * rv.z + tv.w * rv.w;
        }
        op[idx] = val;
    }
}

// ---------------------------------------------------------------------------
extern "C" void kernel_launch(void* const* d_in, const int* in_sizes, int n_in,
                              void* d_out, int out_size, void* d_ws, size_t ws_size,
                              hipStream_t stream) {
    const float* src    = (const float*)d_in[0];
    const float* lin    = (const float*)d_in[1];
    const float* asrc   = (const float*)d_in[2];
    const float* adst   = (const float*)d_in[3];
    const float* sp0_W1 = (const float*)d_in[4];
    const float* sp0_b1 = (const float*)d_in[5];
    const float* sp0_W2 = (const float*)d_in[6];
    const float* sp0_b2 = (const float*)d_in[7];
    const float* sp1_W1 = (const float*)d_in[8];
    const float* sp1_b1 = (const float*)d_in[9];
    const float* sp1_W2 = (const float*)d_in[10];
    const float* sp1_b2 = (const float*)d_in[11];
    const float* tp0_W1 = (const float*)d_in[12];
    const float* tp0_b1 = (const float*)d_in[13];
    const float* tp0_W2 = (const float*)d_in[14];
    const float* tp0_b2 = (const float*)d_in[15];
    const float* tp1_W1 = (const float*)d_in[16];
    const float* tp1_b1 = (const float*)d_in[17];
    const float* tp1_W2 = (const float*)d_in[18];
    const float* tp1_b2 = (const float*)d_in[19];
    const float* sl0    = (const float*)d_in[20];
    const float* sr0    = (const float*)d_in[21];
    const float* sl1    = (const float*)d_in[22];
    const float* sr1    = (const float*)d_in[23];
    const float* tl0    = (const float*)d_in[24];
    const float* tr0    = (const float*)d_in[25];
    const float* tl1    = (const float*)d_in[26];
    const float* tr1    = (const float*)d_in[27];

    float* out_s = (float*)d_out;                 // (4096,4,25,25)
    float* out_t = out_s + 10240000;              // (1600,4,64,64)

    float* ws   = (float*)d_ws;
    float* wbuf = ws;                             // 3072 used (reserve 4096)
    float* wT   = ws + 4096;                      // 20480
    float* region = ws + 24576;

    float* sp0_W1T = wT;
    float* sp1_W1T = wT + 4096;
    float* tp0_W1T = wT + 8192;
    float* tp1_W1T = wT + 12288;
    float* sp0_W2T = wT + 16384;                  // 64x12
    float* sp1_W2T = wT + 17152;                  // 64x8
    float* tp0_W2T = wT + 17664;                  // 64x32
    float* tp1_W2T = wT + 19712;                  // 64x12

    // spatial aliases
    float* xs  = region;                          // 4096*25*64
    float* xs1 = xs + 6553600;                    // 4096*12*64
    float* xs2 = xs1 + 3145728;                   // 4096*5*64
    float* as1 = xs2 + 1310720;                   // 4096*4*12*12
    float* as2 = as1 + 2359296;                   // 4096*4*5*5
    // temporal aliases (region reused; branches sequential)
    float* xt  = region;                          // 1600*64*64
    float* xt1 = xt + 6553600;                    // 1600*32*64
    float* xt2 = xt1 + 3276800;                   // 1600*12*64
    float* at1 = xt2 + 1228800;                   // 1600*4*32*32
    float* at2 = at1 + 6553600;                   // 1600*4*12*12

    wprep_kernel<<<6, 256, 0, stream>>>(lin, asrc, adst, wbuf);
    wtrans_kernel<<<80, 256, 0, stream>>>(sp0_W1, sp1_W1, tp0_W1, tp1_W1,
                                          sp0_W2, sp1_W2, tp0_W2, tp1_W2, wT);

    // ---- spatial branch ----
    xs_kernel<<<4096, 256, 0, stream>>>(src, xs);
    pool_kernel<25, 12, 12><<<4096, 256, 0, stream>>>(xs, sp0_W1T, sp0_b1, sp0_W2T, sp0_b2, xs1);
    gat_kernel<12><<<4096, 256, 0, stream>>>(xs1, wbuf + 1 * 512, as1);
    pool_kernel<12, 5, 8><<<4096, 256, 0, stream>>>(xs1, sp1_W1T, sp1_b1, sp1_W2T, sp1_b2, xs2);
    gat_kernel<5><<<4096, 256, 0, stream>>>(xs2, wbuf + 2 * 512, as2);
    gatfuse_s<<<4096, 256, 0, stream>>>(xs, wbuf + 0 * 512, as1, sl0, sr0, as2, sl1, sr1, out_s);

    // ---- temporal branch ----
    xt_kernel<<<1600, 256, 0, stream>>>(src, xt);
    pool_kernel<64, 32, 32><<<1600, 256, 0, stream>>>(xt, tp0_W1T, tp0_b1, tp0_W2T, tp0_b2, xt1);
    gat_kernel<32><<<1600, 256, 0, stream>>>(xt1, wbuf + 4 * 512, at1);
    pool_kernel<32, 12, 12><<<1600, 256, 0, stream>>>(xt1, tp1_W1T, tp1_b1, tp1_W2T, tp1_b2, xt2);
    gat_kernel<12><<<1600, 256, 0, stream>>>(xt2, wbuf + 5 * 512, at2);
    gatfuse_t<<<6400, 256, 0, stream>>>(xt, wbuf + 3 * 512, at1, tl0, tr0, at2, tl1, tr1, out_t);
}

// Round 10
// 385.742 us; speedup vs baseline: 1.2013x; 1.0869x over previous
//
#include <hip/hip_runtime.h>

#define DEVINL __device__ __forceinline__

DEVINL float leaky(float v) { return v >= 0.f ? v : 0.2f * v; }

typedef float v4f __attribute__((ext_vector_type(4)));

DEVINL void nt_store4(float* p, float4 v) {
    v4f q = {v.x, v.y, v.z, v.w};
    __builtin_nontemporal_store(q, (v4f*)p);
}

// ---------------------------------------------------------------------------
// Precompute per-level head projection vectors.
// ---------------------------------------------------------------------------
__global__ void wprep_kernel(const float* __restrict__ lin,   // (6,64,64)
                             const float* __restrict__ asrc,  // (6,4,16)
                             const float* __restrict__ adst,  // (6,4,16)
                             float* __restrict__ w_out) {     // (6,2,4,64)
    int idx = blockIdx.x * blockDim.x + threadIdx.x;
    if (idx >= 6 * 4 * 64) return;
    int c = idx & 63;
    int h = (idx >> 6) & 3;
    int k = idx >> 8;
    const float* L = lin + k * 64 * 64;
    float s1 = 0.f, s2 = 0.f;
    for (int e = 0; e < 16; ++e) {
        float w = L[(h * 16 + e) * 64 + c];
        s1 += w * asrc[(k * 4 + h) * 16 + e];
        s2 += w * adst[(k * 4 + h) * 16 + e];
    }
    w_out[(k * 2 + 0) * 256 + h * 64 + c] = s1;
    w_out[(k * 2 + 1) * 256 + h * 64 + c] = s2;
}

// ---------------------------------------------------------------------------
// Transpose pool weights once.
// ---------------------------------------------------------------------------
__global__ void wtrans_kernel(const float* __restrict__ s0, const float* __restrict__ s1,
                              const float* __restrict__ t0, const float* __restrict__ t1,
                              const float* __restrict__ s0w2, const float* __restrict__ s1w2,
                              const float* __restrict__ t0w2, const float* __restrict__ t1w2,
                              float* __restrict__ o) {
    int idx = blockIdx.x * 256 + threadIdx.x;
    if (idx < 16384) {
        int m = idx >> 12, r = idx & 4095, c = r >> 6, d = r & 63;
        const float* src = (m == 0) ? s0 : (m == 1) ? s1 : (m == 2) ? t0 : t1;
        o[idx] = src[d * 64 + c];
    } else if (idx < 16384 + 768) {
        int j = idx - 16384, c = j / 12, k = j - 12 * c;
        o[idx] = s0w2[k * 64 + c];
    } else if (idx < 17152 + 512) {
        int j = idx - 17152, c = j >> 3, k = j & 7;
        o[idx] = (k < 5) ? s1w2[k * 64 + c] : 0.f;
    } else if (idx < 17664 + 2048) {
        int j = idx - 17664, c = j >> 5, k = j & 31;
        o[idx] = t0w2[k * 64 + c];
    } else if (idx < 19712 + 768) {
        int j = idx - 19712, c = j / 12, k = j - 12 * c;
        o[idx] = t1w2[k * 64 + c];
    }
}

// ---------------------------------------------------------------------------
// Transposes: src (B=64, C=64, T=64, J=25)
// ---------------------------------------------------------------------------
__global__ void xs_kernel(const float* __restrict__ src, float* __restrict__ xs) {
    int g = blockIdx.x;             // b*64 + t
    int b = g >> 6, t = g & 63;
    __shared__ float tile[64][26];  // [c][j]
    const float* sp = src + b * 102400 + t * 25;
    for (int idx = threadIdx.x; idx < 64 * 25; idx += blockDim.x) {
        int c = idx / 25, j = idx - c * 25;
        tile[c][j] = sp[c * 1600 + j];
    }
    __syncthreads();
    float* op = xs + g * 25 * 64;
    for (int idx = threadIdx.x; idx < 25 * 64; idx += blockDim.x) {
        int j = idx >> 6, c = idx & 63;
        op[idx] = tile[c][j];
    }
}

__global__ void xt_kernel(const float* __restrict__ src, float* __restrict__ xt) {
    int g = blockIdx.x;             // b*25 + j
    int b = g / 25, j = g - b * 25;
    __shared__ float tile[64][65];  // [c][t]
    const float* sp = src + b * 102400 + j;
    for (int idx = threadIdx.x; idx < 64 * 64; idx += blockDim.x) {
        int c = idx >> 6, t = idx & 63;
        tile[c][t] = sp[c * 1600 + t * 25];
    }
    __syncthreads();
    float* op = xt + g * 64 * 64;
    for (int idx = threadIdx.x; idx < 64 * 64; idx += blockDim.x) {
        int t = idx >> 6, c = idx & 63;
        op[idx] = tile[c][t];
    }
}

// ---------------------------------------------------------------------------
// GAT attention (intermediate levels): rank-1 factored softmax, row-major
// coalesced writes.
// ---------------------------------------------------------------------------
template <int N>
__global__ __launch_bounds__(256) void gat_kernel(
    const float* __restrict__ x,  // (G,N,64)
    const float* __restrict__ w,  // [2][4][64] (src, dst)
    float* __restrict__ att) {    // (G,4,N,N)
    int g = blockIdx.x;
    const int tid = threadIdx.x;
    __shared__ float xlT[64][N + 1];  // [c][n]
    __shared__ float wl[512];
    __shared__ float a1s[4 * N], a2s[4 * N];
    __shared__ float rE[4 * N], rF[4 * N], cE[4 * N], cF[4 * N];
    __shared__ float mxs[4];
    const float* xp = x + (size_t)g * N * 64;
    for (int idx = tid; idx < N * 64; idx += 256) {
        int n = idx >> 6, c = idx & 63;
        xlT[c][n] = xp[idx];
    }
    for (int idx = tid; idx < 512; idx += 256) wl[idx] = w[idx];
    __syncthreads();
    for (int idx = tid; idx < 8 * N; idx += 256) {
        int n = idx % N;
        int hh = (idx / N) & 3;
        int sd = idx / (4 * N);
        const float* wp = wl + sd * 256 + hh * 64;
        float acc = 0.f;
        #pragma unroll 8
        for (int c = 0; c < 64; ++c) acc += xlT[c][n] * wp[c];
        (sd == 0 ? a1s : a2s)[hh * N + n] = acc;
    }
    __syncthreads();
    if (tid < 4) {
        float m = -1e30f;
        for (int i = 0; i < N; ++i) m = fmaxf(m, a2s[tid * N + i]);
        mxs[tid] = m;
    }
    __syncthreads();
    for (int idx = tid; idx < 4 * N; idx += 256) {
        int hh = idx / N;
        float d = a2s[idx] - mxs[hh];
        rE[idx] = __expf(d);
        rF[idx] = __expf(0.2f * d);
    }
    __syncthreads();
    for (int idx = tid; idx < 4 * N; idx += 256) {
        int hh = idx / N;
        float a = a1s[idx], mx = mxs[hh];
        float mj = leaky(a + mx);
        float E = __expf(a + mx - mj);
        float F = __expf(0.2f * (a + mx) - mj);
        float S1 = 0.f, S2 = 0.f;
        for (int i = 0; i < N; ++i) {
            bool c = (a + a2s[hh * N + i] >= 0.f);
            S1 += c ? rE[hh * N + i] : 0.f;
            S2 += c ? 0.f : rF[hh * N + i];
        }
        float iv = 1.f / (E * S1 + F * S2);
        cE[idx] = E * iv;
        cF[idx] = F * iv;
    }
    __syncthreads();
    float* ob = att + (size_t)g * 4 * N * N;
    if constexpr ((N % 4) == 0) {
        constexpr int NF4 = N / 4;
        for (int idx = tid; idx < 4 * N * NF4; idx += 256) {
            int row = idx / NF4;           // h*N + i
            int j0 = (idx - row * NF4) * 4;
            int hh = row / N;
            float4 q1 = *(const float4*)&a1s[hh * N + j0];
            float4 qE = *(const float4*)&cE[hh * N + j0];
            float4 qF = *(const float4*)&cF[hh * N + j0];
            float a2i = a2s[row];
            float rEi = rE[row], rFi = rF[row];
            float a1v[4] = {q1.x, q1.y, q1.z, q1.w};
            float ev[4] = {qE.x, qE.y, qE.z, qE.w};
            float fv[4] = {qF.x, qF.y, qF.z, qF.w};
            float r[4];
            #pragma unroll
            for (int c = 0; c < 4; ++c)
                r[c] = (a1v[c] + a2i >= 0.f) ? ev[c] * rEi : fv[c] * rFi;
            *(float4*)&ob[row * N + j0] = make_float4(r[0], r[1], r[2], r[3]);
        }
    } else {
        for (int idx = tid; idx < 4 * N * N; idx += 256) {
            int hh = idx / (N * N), rem = idx - hh * N * N;
            int i = rem / N, j = rem - i * N;
            bool cnd = (a1s[hh * N + j] + a2s[hh * N + i] >= 0.f);
            ob[idx] = cnd ? cE[hh * N + j] * rE[hh * N + i]
                          : cF[hh * N + j] * rF[hh * N + i];
        }
    }
}

// ---------------------------------------------------------------------------
// Diff-pool, register-tiled (round-4 version, measured good).
// ---------------------------------------------------------------------------
template <int N, int K, int KP>
__global__ __launch_bounds__(256, 3) void pool_kernel(
    const float* __restrict__ x,    // (G,N,64)
    const float* __restrict__ W1T,  // (64,64) [c][d]
    const float* __restrict__ b1,   // (64)
    const float* __restrict__ W2T,  // (64,KP) [d][k], pad cols zero
    const float* __restrict__ b2,   // (K)
    float* __restrict__ xo) {       // (G,K,64)
    constexpr int NP = (N + 3) & ~3;
    constexpr int LDN = NP + 1;
    __shared__ float xlT[64 * LDN];  // [c][n]
    __shared__ float yT[64 * LDN];   // [d][n]
    __shared__ float sT[KP * LDN];   // [k][n]
    const int g = blockIdx.x, tid = threadIdx.x;
    const float* xp = x + (size_t)g * N * 64;
    for (int i4 = tid; i4 < N * 16; i4 += 256) {
        int n = i4 >> 4, c0 = (i4 & 15) << 2;
        float4 v = ((const float4*)xp)[i4];
        xlT[(c0 + 0) * LDN + n] = v.x;
        xlT[(c0 + 1) * LDN + n] = v.y;
        xlT[(c0 + 2) * LDN + n] = v.z;
        xlT[(c0 + 3) * LDN + n] = v.w;
    }
    if constexpr (NP > N) {
        for (int i = tid; i < 64 * (NP - N); i += 256) {
            int c = i / (NP - N), n = N + i % (NP - N);
            xlT[c * LDN + n] = 0.f;
        }
    }
    __syncthreads();
    constexpr int T1 = (NP / 4) * 16;
    if (tid < T1) {
        int d0 = (tid & 15) << 2, n0 = (tid >> 4) << 2;
        float acc[4][4] = {};
        #pragma unroll 4
        for (int c = 0; c < 64; ++c) {
            float4 w4 = *(const float4*)(W1T + c * 64 + d0);
            float wv[4] = {w4.x, w4.y, w4.z, w4.w};
            float xv[4];
            #pragma unroll
            for (int r = 0; r < 4; ++r) xv[r] = xlT[c * LDN + n0 + r];
            #pragma unroll
            for (int r = 0; r < 4; ++r)
                #pragma unroll
                for (int cc = 0; cc < 4; ++cc) acc[r][cc] += xv[r] * wv[cc];
        }
        float4 b4 = *(const float4*)(b1 + d0);
        float bb[4] = {b4.x, b4.y, b4.z, b4.w};
        #pragma unroll
        for (int r = 0; r < 4; ++r)
            #pragma unroll
            for (int cc = 0; cc < 4; ++cc)
                yT[(d0 + cc) * LDN + n0 + r] = fmaxf(acc[r][cc] + bb[cc], 0.f);
    }
    __syncthreads();
    constexpr int KG4 = KP / 4;
    constexpr int T2 = (NP / 4) * KG4;
    if (tid < T2) {
        int k0 = (tid % KG4) << 2, n0 = (tid / KG4) << 2;
        float acc[4][4] = {};
        #pragma unroll 4
        for (int d = 0; d < 64; ++d) {
            float4 w4 = *(const float4*)(W2T + d * KP + k0);
            float wv[4] = {w4.x, w4.y, w4.z, w4.w};
            float yv[4];
            #pragma unroll
            for (int r = 0; r < 4; ++r) yv[r] = yT[d * LDN + n0 + r];
            #pragma unroll
            for (int r = 0; r < 4; ++r)
                #pragma unroll
                for (int cc = 0; cc < 4; ++cc) acc[r][cc] += yv[r] * wv[cc];
        }
        #pragma unroll
        for (int cc = 0; cc < 4; ++cc) {
            int k = k0 + cc;
            float bb = (k < K) ? b2[k] : 0.f;
            #pragma unroll
            for (int r = 0; r < 4; ++r)
                sT[k * LDN + n0 + r] = (k < K) ? (acc[r][cc] + bb) : -1e30f;
        }
    }
    __syncthreads();
    if (tid < NP) {
        float m = -1e30f;
        #pragma unroll
        for (int k = 0; k < KP; ++k) m = fmaxf(m, sT[k * LDN + tid]);
        float sum = 0.f;
        float e[KP];
        #pragma unroll
        for (int k = 0; k < KP; ++k) { e[k] = __expf(sT[k * LDN + tid] - m); sum += e[k]; }
        float inv = 1.f / sum;
        #pragma unroll
        for (int k = 0; k < KP; ++k) sT[k * LDN + tid] = e[k] * inv;
    }
    __syncthreads();
    constexpr int KG2 = (K + 1) / 2;
    constexpr int T3 = KG2 * 16;
    if (tid < T3) {
        int k0 = (tid % KG2) * 2, c0 = (tid / KG2) * 4;
        float acc0[4] = {}, acc1[4] = {};
        #pragma unroll 4
        for (int n = 0; n < N; ++n) {
            float sv0 = sT[k0 * LDN + n];
            float sv1 = sT[(k0 + 1) * LDN + n];
            float xv[4];
            #pragma unroll
            for (int j = 0; j < 4; ++j) xv[j] = xlT[(c0 + j) * LDN + n];
            #pragma unroll
            for (int j = 0; j < 4; ++j) { acc0[j] += sv0 * xv[j]; acc1[j] += sv1 * xv[j]; }
        }
        float* op = xo + (size_t)g * K * 64;
        *(float4*)&op[k0 * 64 + c0] = make_float4(acc0[0], acc0[1], acc0[2], acc0[3]);
        if (k0 + 1 < K)
            *(float4*)&op[(k0 + 1) * 64 + c0] = make_float4(acc1[0], acc1[1], acc1[2], acc1[3]);
    }
}

// ---------------------------------------------------------------------------
// Fused GAT0 + low-rank fuse, temporal. Rank-1 softmax, padded A1, R1/R2
// staged in LDS (L2-traffic fix), wave-overlapped phases, NT output stores.
// Block=(g,h) XCD-swizzled. LDS ~29 KB -> 5 blocks/CU.
// ---------------------------------------------------------------------------
__global__ __launch_bounds__(256, 5) void gatfuse_t(
    const float* __restrict__ x,    // (1600,64,64)
    const float* __restrict__ w,    // [2][4][64]
    const float* __restrict__ A1g,  // (1600,4,32,32)
    const float* __restrict__ L1,   // (4,64,32)
    const float* __restrict__ R1,   // (4,32,64)
    const float* __restrict__ A2g,  // (1600,4,12,12)
    const float* __restrict__ L2,   // (4,64,12)
    const float* __restrict__ R2,   // (4,12,64)
    float* __restrict__ out)        // (1600,4,64,64)
{
    const int bid = blockIdx.x;
    const int g = (bid & 7) | ((bid >> 5) << 3);   // 4 heads of one g -> same XCD
    const int h = (bid >> 3) & 3;
    const int tid = threadIdx.x;
    __shared__ float t1T[32 * 64];   // [l][j]
    __shared__ float t2T[12 * 64];   // [l][j]
    __shared__ float r1l[32 * 64];   // [l][m]
    __shared__ float r2l[12 * 64];   // [l][m]
    __shared__ float A1[32 * 36];    // [k][l], padded
    __shared__ float A2[12 * 13];    // [k][l]
    __shared__ float a01[64], a02[64];
    __shared__ float rEs[64], rFs[64], cEs[64], cFs[64];

    // ---- phase 1: scores (waves 0-1) || stage A1/A2/R1/R2 (waves 2-3)
    if (tid < 128) {
        int t = tid & 63, sd = tid >> 6;
        const float4* xr = (const float4*)(x + (size_t)g * 4096 + t * 64);
        const float* wv = w + sd * 256 + h * 64;
        float acc = 0.f;
        #pragma unroll
        for (int q = 0; q < 16; ++q) {
            float4 xv = xr[q];
            float4 w4 = *(const float4*)(wv + q * 4);
            acc += xv.x * w4.x + xv.y * w4.y + xv.z * w4.z + xv.w * w4.w;
        }
        (sd == 0 ? a01 : a02)[t] = acc;
    } else {
        int u = tid - 128;
        const float* a1p = A1g + (size_t)(g * 4 + h) * 1024;
        #pragma unroll
        for (int q = 0; q < 8; ++q) {
            int idx = q * 128 + u;                 // = k*32 + l
            A1[(idx >> 5) * 36 + (idx & 31)] = a1p[idx];
        }
        const float* a2p = A2g + (size_t)(g * 4 + h) * 144;
        for (int idx = u; idx < 144; idx += 128) {
            int k = idx / 12, l = idx - k * 12;
            A2[k * 13 + l] = a2p[idx];
        }
        const float4* r1p = (const float4*)(R1 + (size_t)h * 2048);
        #pragma unroll
        for (int q = 0; q < 4; ++q) ((float4*)r1l)[q * 128 + u] = r1p[q * 128 + u];
        const float4* r2p = (const float4*)(R2 + (size_t)h * 768);
        for (int idx = u; idx < 192; idx += 128) ((float4*)r2l)[idx] = r2p[idx];
    }
    __syncthreads();

    // ---- phase 2: wave 0 = row factors; waves 1-3 = t1T rows 8..31
    if (tid < 64) {
        float mx = a02[0];
        for (int i = 1; i < 64; ++i) mx = fmaxf(mx, a02[i]);
        float d = a02[tid] - mx;
        rEs[tid] = __expf(d);
        rFs[tid] = __expf(0.2f * d);
        cEs[tid] = mx;   // stash mx (overwritten in phase 3)
    } else {
        const int j = tid & 63, l0 = (tid >> 6) * 8;   // l0 = 8,16,24
        float lj[32];
        const float4* lp = (const float4*)(L1 + ((size_t)h * 64 + j) * 32);
        #pragma unroll
        for (int q = 0; q < 8; ++q) {
            float4 v = lp[q];
            lj[q * 4] = v.x; lj[q * 4 + 1] = v.y; lj[q * 4 + 2] = v.z; lj[q * 4 + 3] = v.w;
        }
        float acc8[8] = {};
        for (int k = 0; k < 32; ++k) {
            float lk = lj[k];
            float4 a4a = *(const float4*)&A1[k * 36 + l0];
            float4 a4b = *(const float4*)&A1[k * 36 + l0 + 4];
            acc8[0] += lk * a4a.x; acc8[1] += lk * a4a.y;
            acc8[2] += lk * a4a.z; acc8[3] += lk * a4a.w;
            acc8[4] += lk * a4b.x; acc8[5] += lk * a4b.y;
            acc8[6] += lk * a4b.z; acc8[7] += lk * a4b.w;
        }
        #pragma unroll
        for (int lo = 0; lo < 8; ++lo) t1T[(l0 + lo) * 64 + j] = acc8[lo];
    }
    __syncthreads();

    // ---- phase 3: wave0 = col factors; wave1 = t1T rows 0-7; waves 2-3 = t2T
    if (tid < 64) {
        float mx = cEs[tid];
        float a = a01[tid];
        float mj = leaky(a + mx);
        float E = __expf(a + mx - mj);
        float F = __expf(0.2f * (a + mx) - mj);
        float S1 = 0.f, S2 = 0.f;
        for (int i = 0; i < 64; ++i) {
            bool c = (a + a02[i] >= 0.f);
            S1 += c ? rEs[i] : 0.f;
            S2 += c ? 0.f : rFs[i];
        }
        float iv = 1.f / (E * S1 + F * S2);
        cEs[tid] = E * iv;
        cFs[tid] = F * iv;
    } else if (tid < 128) {
        const int j = tid & 63;
        float lj[32];
        const float4* lp = (const float4*)(L1 + ((size_t)h * 64 + j) * 32);
        #pragma unroll
        for (int q = 0; q < 8; ++q) {
            float4 v = lp[q];
            lj[q * 4] = v.x; lj[q * 4 + 1] = v.y; lj[q * 4 + 2] = v.z; lj[q * 4 + 3] = v.w;
        }
        float acc8[8] = {};
        for (int k = 0; k < 32; ++k) {
            float lk = lj[k];
            float4 a4a = *(const float4*)&A1[k * 36];
            float4 a4b = *(const float4*)&A1[k * 36 + 4];
            acc8[0] += lk * a4a.x; acc8[1] += lk * a4a.y;
            acc8[2] += lk * a4a.z; acc8[3] += lk * a4a.w;
            acc8[4] += lk * a4b.x; acc8[5] += lk * a4b.y;
            acc8[6] += lk * a4b.z; acc8[7] += lk * a4b.w;
        }
        #pragma unroll
        for (int lo = 0; lo < 8; ++lo) t1T[lo * 64 + j] = acc8[lo];
    } else {
        const int j = tid & 63, lb = ((tid >> 6) - 2) * 6;   // 0 or 6
        float lj2[12];
        const float4* lp2 = (const float4*)(L2 + ((size_t)h * 64 + j) * 12);
        #pragma unroll
        for (int q = 0; q < 3; ++q) {
            float4 v = lp2[q];
            lj2[q * 4] = v.x; lj2[q * 4 + 1] = v.y;
            lj2[q * 4 + 2] = v.z; lj2[q * 4 + 3] = v.w;
        }
        #pragma unroll
        for (int lo = 0; lo < 6; ++lo) {
            int l = lb + lo;
            float acc = 0.f;
            #pragma unroll
            for (int k = 0; k < 12; ++k) acc += lj2[k] * A2[k * 13 + l];
            t2T[l * 64 + j] = acc;
        }
    }
    __syncthreads();

    // ---- main 4x4 register-tiled output (all LDS operands), NT stores
    const int i0 = (tid >> 4) << 2, m0 = (tid & 15) << 2;
    float acc[4][4];
    {
        float4 qa1 = *(const float4*)&a01[m0];
        float4 qcE = *(const float4*)&cEs[m0];
        float4 qcF = *(const float4*)&cFs[m0];
        float4 qa2 = *(const float4*)&a02[i0];
        float4 qrE = *(const float4*)&rEs[i0];
        float4 qrF = *(const float4*)&rFs[i0];
        float a1v[4] = {qa1.x, qa1.y, qa1.z, qa1.w};
        float ev[4] = {qcE.x, qcE.y, qcE.z, qcE.w};
        float fv[4] = {qcF.x, qcF.y, qcF.z, qcF.w};
        float a2v[4] = {qa2.x, qa2.y, qa2.z, qa2.w};
        float rev[4] = {qrE.x, qrE.y, qrE.z, qrE.w};
        float rfv[4] = {qrF.x, qrF.y, qrF.z, qrF.w};
        #pragma unroll
        for (int r = 0; r < 4; ++r)
            #pragma unroll
            for (int c = 0; c < 4; ++c)
                acc[r][c] = (a1v[c] + a2v[r] >= 0.f) ? ev[c] * rev[r]
                                                     : fv[c] * rfv[r];
    }
    #pragma unroll 8
    for (int l = 0; l < 32; ++l) {
        float4 t4 = *(const float4*)&t1T[l * 64 + i0];
        float4 r4 = *(const float4*)&r1l[l * 64 + m0];
        float tv[4] = {t4.x, t4.y, t4.z, t4.w};
        float rv[4] = {r4.x, r4.y, r4.z, r4.w};
        #pragma unroll
        for (int r = 0; r < 4; ++r)
            #pragma unroll
            for (int c = 0; c < 4; ++c) acc[r][c] += tv[r] * rv[c];
    }
    #pragma unroll 4
    for (int l = 0; l < 12; ++l) {
        float4 t4 = *(const float4*)&t2T[l * 64 + i0];
        float4 r4 = *(const float4*)&r2l[l * 64 + m0];
        float tv[4] = {t4.x, t4.y, t4.z, t4.w};
        float rv[4] = {r4.x, r4.y, r4.z, r4.w};
        #pragma unroll
        for (int r = 0; r < 4; ++r)
            #pragma unroll
            for (int c = 0; c < 4; ++c) acc[r][c] += tv[r] * rv[c];
    }
    float* op = out + ((size_t)g * 4 + h) * 4096;
    #pragma unroll
    for (int r = 0; r < 4; ++r)
        nt_store4(&op[(i0 + r) * 64 + m0],
                  make_float4(acc[r][0], acc[r][1], acc[r][2], acc[r][3]));
}

// ---------------------------------------------------------------------------
// Fused GAT0 + fuse, spatial. Rank-1 softmax, NT output stores.
// ---------------------------------------------------------------------------
__global__ __launch_bounds__(256, 5) void gatfuse_s(
    const float* __restrict__ x,    // (4096,25,64)
    const float* __restrict__ w,    // [2][4][64]
    const float* __restrict__ A1g,  // (4096,4,12,12)
    const float* __restrict__ L1,   // (4,25,12)
    const float* __restrict__ R1,   // (4,12,25)
    const float* __restrict__ A2g,  // (4096,4,5,5)
    const float* __restrict__ L2,   // (4,25,5)
    const float* __restrict__ R2,   // (4,5,25)
    float* __restrict__ out)        // (4096,4,25,25)
{
    const int g = blockIdx.x;
    const int tid = threadIdx.x;
    const int h = tid >> 6, t = tid & 63;
    __shared__ float xl[25 * 68];
    __shared__ float A1[4][12 * 13];   // [k][l]
    __shared__ float A2[4][5 * 6];     // [k][l]
    __shared__ float t1l[4][25 * 16];  // [i][l] pad zero
    __shared__ float t2l[4][25 * 8];   // [i][l] pad zero
    __shared__ float r1T[4][25 * 16];  // [m][l] pad zero
    __shared__ float r2T[4][25 * 8];   // [m][l] pad zero
    __shared__ float a01[4][25], a02[4][25];
    __shared__ float rE[4][25], rF[4][25], cE[4][25], cF[4][25];
    __shared__ float mxs[4];

    const float* xp = x + (size_t)g * 1600;
    for (int idx = tid; idx < 400; idx += 256) {
        int n = idx >> 4, c0 = (idx & 15) << 2;
        *(float4*)&xl[n * 68 + c0] = *(const float4*)(xp + n * 64 + c0);
    }
    const float* a1p = A1g + (size_t)(g * 4 + h) * 144;
    for (int idx = t; idx < 144; idx += 64) {
        int k = idx / 12, l = idx - k * 12;
        A1[h][k * 13 + l] = a1p[idx];
    }
    const float* a2p = A2g + (size_t)(g * 4 + h) * 25;
    if (t < 25) {
        int k = t / 5, l = t - (t / 5) * 5;
        A2[h][k * 6 + l] = a2p[t];
    }
    for (int idx = t; idx < 400; idx += 64) {
        int m = idx >> 4, l = idx & 15;
        r1T[h][idx] = (l < 12) ? R1[h * 300 + l * 25 + m] : 0.f;
    }
    for (int idx = t; idx < 200; idx += 64) {
        int m = idx >> 3, l = idx & 7;
        r2T[h][idx] = (l < 5) ? R2[h * 125 + l * 25 + m] : 0.f;
    }
    __syncthreads();

    if (t < 25) {
        const float* ws_ = w + h * 64;
        const float* wd_ = w + 256 + h * 64;
        const float* xr = &xl[t * 68];
        float s1 = 0.f, s2 = 0.f;
        #pragma unroll
        for (int c = 0; c < 64; c += 4) {
            float4 xv = *(const float4*)&xr[c];
            float4 w1 = *(const float4*)(ws_ + c);
            float4 w2 = *(const float4*)(wd_ + c);
            s1 += xv.x * w1.x + xv.y * w1.y + xv.z * w1.z + xv.w * w1.w;
            s2 += xv.x * w2.x + xv.y * w2.y + xv.z * w2.z + xv.w * w2.w;
        }
        a01[h][t] = s1;
        a02[h][t] = s2;
    }
    __syncthreads();

    if (t < 25) {
        float mx = a02[h][0];
        for (int i = 1; i < 25; ++i) mx = fmaxf(mx, a02[h][i]);
        if (t == 0) mxs[h] = mx;
        float d = a02[h][t] - mx;
        rE[h][t] = __expf(d);
        rF[h][t] = __expf(0.2f * d);
    } else if (t >= 32 && t < 57) {
        int i = t - 32;
        float lj[12];
        const float4* lp = (const float4*)(L1 + ((size_t)h * 25 + i) * 12);
        #pragma unroll
        for (int q = 0; q < 3; ++q) {
            float4 v = lp[q];
            lj[q * 4] = v.x; lj[q * 4 + 1] = v.y; lj[q * 4 + 2] = v.z; lj[q * 4 + 3] = v.w;
        }
        #pragma unroll
        for (int l = 0; l < 12; ++l) {
            float acc = 0.f;
            #pragma unroll
            for (int k = 0; k < 12; ++k) acc += lj[k] * A1[h][k * 13 + l];
            t1l[h][i * 16 + l] = acc;
        }
        #pragma unroll
        for (int l = 12; l < 16; ++l) t1l[h][i * 16 + l] = 0.f;
        float lj2[5];
        const float* lp2 = L2 + ((size_t)h * 25 + i) * 5;
        #pragma unroll
        for (int k = 0; k < 5; ++k) lj2[k] = lp2[k];
        #pragma unroll
        for (int l = 0; l < 5; ++l) {
            float acc = 0.f;
            #pragma unroll
            for (int k = 0; k < 5; ++k) acc += lj2[k] * A2[h][k * 6 + l];
            t2l[h][i * 8 + l] = acc;
        }
        #pragma unroll
        for (int l = 5; l < 8; ++l) t2l[h][i * 8 + l] = 0.f;
    }
    __syncthreads();

    if (t < 25) {
        float a = a01[h][t], mx = mxs[h];
        float mj = leaky(a + mx);
        float E = __expf(a + mx - mj);
        float F = __expf(0.2f * (a + mx) - mj);
        float S1 = 0.f, S2 = 0.f;
        for (int i = 0; i < 25; ++i) {
            bool c = (a + a02[h][i] >= 0.f);
            S1 += c ? rE[h][i] : 0.f;
            S2 += c ? 0.f : rF[h][i];
        }
        float iv = 1.f / (E * S1 + F * S2);
        cE[h][t] = E * iv;
        cF[h][t] = F * iv;
    }
    __syncthreads();

    float* op = out + ((size_t)g * 4 + h) * 625;
    for (int idx = t; idx < 625; idx += 64) {
        int i = idx / 25, m = idx - i * 25;
        bool cnd = (a01[h][m] + a02[h][i] >= 0.f);
        float val = cnd ? cE[h][m] * rE[h][i] : cF[h][m] * rF[h][i];
        const float* t1r = &t1l[h][i * 16];
        const float* r1c = &r1T[h][m * 16];
        #pragma unroll
        for (int q = 0; q < 4; ++q) {
            float4 tv = *(const float4*)&t1r[q * 4];
            float4 rv = *(const float4*)&r1c[q * 4];
            val += tv.x * rv.x + tv.y * rv.y + tv.z * rv.z + tv.w * rv.w;
        }
        const float* t2r = &t2l[h][i * 8];
        const float* r2c = &r2T[h][m * 8];
        #pragma unroll
        for (int q = 0; q < 2; ++q) {
            float4 tv = *(const float4*)&t2r[q * 4];
            float4 rv = *(const float4*)&r2c[q * 4];
            val += tv.x * rv.x + tv.y * rv.y + tv.z * rv.z + tv.w * rv.w;
        }
        __builtin_nontemporal_store(val, &op[idx]);
    }
}

// ---------------------------------------------------------------------------
extern "C" void kernel_launch(void* const* d_in, const int* in_sizes, int n_in,
                              void* d_out, int out_size, void* d_ws, size_t ws_size,
                              hipStream_t stream) {
    const float* src    = (const float*)d_in[0];
    const float* lin    = (const float*)d_in[1];
    const float* asrc   = (const float*)d_in[2];
    const float* adst   = (const float*)d_in[3];
    const float* sp0_W1 = (const float*)d_in[4];
    const float* sp0_b1 = (const float*)d_in[5];
    const float* sp0_W2 = (const float*)d_in[6];
    const float* sp0_b2 = (const float*)d_in[7];
    const float* sp1_W1 = (const float*)d_in[8];
    const float* sp1_b1 = (const float*)d_in[9];
    const float* sp1_W2 = (const float*)d_in[10];
    const float* sp1_b2 = (const float*)d_in[11];
    const float* tp0_W1 = (const float*)d_in[12];
    const float* tp0_b1 = (const float*)d_in[13];
    const float* tp0_W2 = (const float*)d_in[14];
    const float* tp0_b2 = (const float*)d_in[15];
    const float* tp1_W1 = (const float*)d_in[16];
    const float* tp1_b1 = (const float*)d_in[17];
    const float* tp1_W2 = (const float*)d_in[18];
    const float* tp1_b2 = (const float*)d_in[19];
    const float* sl0    = (const float*)d_in[20];
    const float* sr0    = (const float*)d_in[21];
    const float* sl1    = (const float*)d_in[22];
    const float* sr1    = (const float*)d_in[23];
    const float* tl0    = (const float*)d_in[24];
    const float* tr0    = (const float*)d_in[25];
    const float* tl1    = (const float*)d_in[26];
    const float* tr1    = (const float*)d_in[27];

    float* out_s = (float*)d_out;                 // (4096,4,25,25)
    float* out_t = out_s + 10240000;              // (1600,4,64,64)

    float* ws   = (float*)d_ws;
    float* wbuf = ws;                             // 3072 used (reserve 4096)
    float* wT   = ws + 4096;                      // 20480
    float* region = ws + 24576;

    float* sp0_W1T = wT;
    float* sp1_W1T = wT + 4096;
    float* tp0_W1T = wT + 8192;
    float* tp1_W1T = wT + 12288;
    float* sp0_W2T = wT + 16384;                  // 64x12
    float* sp1_W2T = wT + 17152;                  // 64x8
    float* tp0_W2T = wT + 17664;                  // 64x32
    float* tp1_W2T = wT + 19712;                  // 64x12

    // spatial aliases
    float* xs  = region;                          // 4096*25*64
    float* xs1 = xs + 6553600;                    // 4096*12*64
    float* xs2 = xs1 + 3145728;                   // 4096*5*64
    float* as1 = xs2 + 1310720;                   // 4096*4*12*12
    float* as2 = as1 + 2359296;                   // 4096*4*5*5
    // temporal aliases (region reused; branches sequential)
    float* xt  = region;                          // 1600*64*64
    float* xt1 = xt + 6553600;                    // 1600*32*64
    float* xt2 = xt1 + 3276800;                   // 1600*12*64
    float* at1 = xt2 + 1228800;                   // 1600*4*32*32
    float* at2 = at1 + 6553600;                   // 1600*4*12*12

    wprep_kernel<<<6, 256, 0, stream>>>(lin, asrc, adst, wbuf);
    wtrans_kernel<<<80, 256, 0, stream>>>(sp0_W1, sp1_W1, tp0_W1, tp1_W1,
                                          sp0_W2, sp1_W2, tp0_W2, tp1_W2, wT);

    // ---- spatial branch ----
    xs_kernel<<<4096, 256, 0, stream>>>(src, xs);
    pool_kernel<25, 12, 12><<<4096, 256, 0, stream>>>(xs, sp0_W1T, sp0_b1, sp0_W2T, sp0_b2, xs1);
    gat_kernel<12><<<4096, 256, 0, stream>>>(xs1, wbuf + 1 * 512, as1);
    pool_kernel<12, 5, 8><<<4096, 256, 0, stream>>>(xs1, sp1_W1T, sp1_b1, sp1_W2T, sp1_b2, xs2);
    gat_kernel<5><<<4096, 256, 0, stream>>>(xs2, wbuf + 2 * 512, as2);
    gatfuse_s<<<4096, 256, 0, stream>>>(xs, wbuf + 0 * 512, as1, sl0, sr0, as2, sl1, sr1, out_s);

    // ---- temporal branch ----
    xt_kernel<<<1600, 256, 0, stream>>>(src, xt);
    pool_kernel<64, 32, 32><<<1600, 256, 0, stream>>>(xt, tp0_W1T, tp0_b1, tp0_W2T, tp0_b2, xt1);
    gat_kernel<32><<<1600, 256, 0, stream>>>(xt1, wbuf + 4 * 512, at1);
    pool_kernel<32, 12, 12><<<1600, 256, 0, stream>>>(xt1, tp1_W1T, tp1_b1, tp1_W2T, tp1_b2, xt2);
    gat_kernel<12><<<1600, 256, 0, stream>>>(xt2, wbuf + 5 * 512, at2);
    gatfuse_t<<<6400, 256, 0, stream>>>(xt, wbuf + 3 * 512, at1, tl0, tr0, at2, tl1, tr1, out_t);
}